// Round 1
// baseline (3420.468 us; speedup 1.0000x reference)
//
#include <hip/hip_runtime.h>

#define N_USERS 400000
#define N_ITEMS 200000
#define NNODES  600000   // N_USERS + N_ITEMS
#define D 64
#define B 8192

// ---------------------------------------------------------------------------
// x[node][c] = (node < N_USERS ? user_emb*um : item_emb*im)
// one thread per 4 elements (float4 path)
// ---------------------------------------------------------------------------
__global__ void k_mask_concat(const float* __restrict__ ue, const float* __restrict__ ie,
                              const int* __restrict__ um, const int* __restrict__ im,
                              float* __restrict__ x) {
    int tid = blockIdx.x * blockDim.x + threadIdx.x;
    const int total = NNODES * (D / 4);
    if (tid >= total) return;
    int node = tid / (D / 4);
    int c4   = (tid % (D / 4)) * 4;
    float4 v; int4 m;
    if (node < N_USERS) {
        v = *(const float4*)(ue + (size_t)node * D + c4);
        m = *(const int4*)(um + (size_t)node * D + c4);
    } else {
        int n2 = node - N_USERS;
        v = *(const float4*)(ie + (size_t)n2 * D + c4);
        m = *(const int4*)(im + (size_t)n2 * D + c4);
    }
    v.x *= (float)m.x; v.y *= (float)m.y; v.z *= (float)m.z; v.w *= (float)m.w;
    *(float4*)(x + (size_t)tid * 4) = v;
}

// ---------------------------------------------------------------------------
// COO SPMM via atomics: y[row] += val * x[col]
// 16 threads per edge, each handling 4 columns (float4 gather, 4 atomics)
// ---------------------------------------------------------------------------
__global__ void k_spmm(const int* __restrict__ rows, const int* __restrict__ cols,
                       const float* __restrict__ vals, const float* __restrict__ x,
                       float* __restrict__ y, int nnz) {
    int tid = blockIdx.x * blockDim.x + threadIdx.x;
    int total = nnz * 16;
    if (tid >= total) return;
    int e  = tid >> 4;
    int c4 = (tid & 15) << 2;
    int col = cols[e];
    int row = rows[e];
    float v = vals[e];
    float4 xv = *(const float4*)(x + (size_t)col * D + c4);
    float* yp = y + (size_t)row * D + c4;
    atomicAdd(yp + 0, v * xv.x);
    atomicAdd(yp + 1, v * xv.y);
    atomicAdd(yp + 2, v * xv.z);
    atomicAdd(yp + 3, v * xv.w);
}

// ---------------------------------------------------------------------------
// Accumulate gathered rows of x into out (first 3 outputs):
//   out = (a*out + gather) * s
// a=0,s=1 : init;  a=1,s=1 : accumulate;  a=1,s=0.25 : final layer + mean
// ---------------------------------------------------------------------------
__global__ void k_gather(const float* __restrict__ x, const int* __restrict__ users,
                         const int* __restrict__ pos, const int* __restrict__ neg,
                         float* __restrict__ out, float a, float s) {
    int tid = blockIdx.x * blockDim.x + threadIdx.x;
    const int per_set = B * (D / 4);
    const int total = 3 * per_set;
    if (tid >= total) return;
    int set = tid / per_set;
    int rem = tid - set * per_set;
    int b   = rem / (D / 4);
    int c4  = (rem % (D / 4)) * 4;
    int node;
    if (set == 0)      node = users[b];
    else if (set == 1) node = N_USERS + pos[b];
    else               node = N_USERS + neg[b];
    float4 g = *(const float4*)(x + (size_t)node * D + c4);
    float* op = out + (size_t)tid * 4;
    float4 o;
    if (a != 0.0f) {
        o = *(const float4*)op;
        o.x = (a * o.x + g.x) * s;
        o.y = (a * o.y + g.y) * s;
        o.z = (a * o.z + g.z) * s;
        o.w = (a * o.w + g.w) * s;
    } else {
        o.x = g.x * s; o.y = g.y * s; o.z = g.z * s; o.w = g.w * s;
    }
    *(float4*)op = o;
}

// ---------------------------------------------------------------------------
// Ego outputs (outputs 3,4,5): masked gathers straight from the embeddings
// ---------------------------------------------------------------------------
__global__ void k_ego(const float* __restrict__ ue, const float* __restrict__ ie,
                      const int* __restrict__ um, const int* __restrict__ im,
                      const int* __restrict__ users, const int* __restrict__ pos,
                      const int* __restrict__ neg, float* __restrict__ out) {
    int tid = blockIdx.x * blockDim.x + threadIdx.x;
    const int per_set = B * (D / 4);
    const int total = 3 * per_set;
    if (tid >= total) return;
    int set = tid / per_set;
    int rem = tid - set * per_set;
    int b   = rem / (D / 4);
    int c4  = (rem % (D / 4)) * 4;
    float4 v; int4 m;
    if (set == 0) {
        int n = users[b];
        v = *(const float4*)(ue + (size_t)n * D + c4);
        m = *(const int4*)(um + (size_t)n * D + c4);
    } else if (set == 1) {
        int n = pos[b];
        v = *(const float4*)(ie + (size_t)n * D + c4);
        m = *(const int4*)(im + (size_t)n * D + c4);
    } else {
        int n = neg[b];
        v = *(const float4*)(ie + (size_t)n * D + c4);
        m = *(const int4*)(im + (size_t)n * D + c4);
    }
    v.x *= (float)m.x; v.y *= (float)m.y; v.z *= (float)m.z; v.w *= (float)m.w;
    *(float4*)(out + (size_t)tid * 4) = v;
}

extern "C" void kernel_launch(void* const* d_in, const int* in_sizes, int n_in,
                              void* d_out, int out_size, void* d_ws, size_t ws_size,
                              hipStream_t stream) {
    const float* ue   = (const float*)d_in[0];
    const float* ie   = (const float*)d_in[1];
    const int*   um   = (const int*)d_in[2];
    const int*   im   = (const int*)d_in[3];
    const int*   rows = (const int*)d_in[4];
    const int*   cols = (const int*)d_in[5];
    const float* vals = (const float*)d_in[6];
    const int*   users = (const int*)d_in[7];
    const int*   pos   = (const int*)d_in[8];
    const int*   neg   = (const int*)d_in[9];
    int nnz = in_sizes[4];

    float* out = (float*)d_out;
    float* X = (float*)d_ws;                       // current layer embeddings
    float* Y = X + (size_t)NNODES * D;             // next layer embeddings

    const int blk = 256;

    // layer-0 embeddings (masked concat)
    int n_mask = NNODES * (D / 4);
    k_mask_concat<<<(n_mask + blk - 1) / blk, blk, 0, stream>>>(ue, ie, um, im, X);

    // init output accumulators with layer-0 gathers; fill ego outputs
    int n_g = 3 * B * (D / 4);
    k_gather<<<(n_g + blk - 1) / blk, blk, 0, stream>>>(X, users, pos, neg, out, 0.0f, 1.0f);
    k_ego<<<(n_g + blk - 1) / blk, blk, 0, stream>>>(ue, ie, um, im, users, pos, neg,
                                                     out + (size_t)3 * B * D);

    // 3 propagation layers
    int n_s = nnz * 16;
    for (int l = 0; l < 3; ++l) {
        hipMemsetAsync(Y, 0, (size_t)NNODES * D * sizeof(float), stream);
        k_spmm<<<(n_s + blk - 1) / blk, blk, 0, stream>>>(rows, cols, vals, X, Y, nnz);
        float s = (l == 2) ? 0.25f : 1.0f;
        k_gather<<<(n_g + blk - 1) / blk, blk, 0, stream>>>(Y, users, pos, neg, out, 1.0f, s);
        float* t = X; X = Y; Y = t;
    }
}

// Round 2
// 790.662 us; speedup vs baseline: 4.3261x; 4.3261x over previous
//
#include <hip/hip_runtime.h>

#define N_USERS 400000
#define N_ITEMS 200000
#define NNODES  600000   // N_USERS + N_ITEMS
#define D 64
#define B 8192

// ---------------------------------------------------------------------------
// x[node][c] = (node < N_USERS ? user_emb*um : item_emb*im)
// ---------------------------------------------------------------------------
__global__ void k_mask_concat(const float* __restrict__ ue, const float* __restrict__ ie,
                              const int* __restrict__ um, const int* __restrict__ im,
                              float* __restrict__ x) {
    int tid = blockIdx.x * blockDim.x + threadIdx.x;
    const int total = NNODES * (D / 4);
    if (tid >= total) return;
    int node = tid / (D / 4);
    int c4   = (tid % (D / 4)) * 4;
    float4 v; int4 m;
    if (node < N_USERS) {
        v = *(const float4*)(ue + (size_t)node * D + c4);
        m = *(const int4*)(um + (size_t)node * D + c4);
    } else {
        int n2 = node - N_USERS;
        v = *(const float4*)(ie + (size_t)n2 * D + c4);
        m = *(const int4*)(im + (size_t)n2 * D + c4);
    }
    v.x *= (float)m.x; v.y *= (float)m.y; v.z *= (float)m.z; v.w *= (float)m.w;
    *(float4*)(x + (size_t)tid * 4) = v;
}

// ---------------------------------------------------------------------------
// CSR build: histogram -> per-block exclusive scan -> block-sums scan -> fixup
// -> scatter edges into row-sorted order
// ---------------------------------------------------------------------------
__global__ void k_hist(const int* __restrict__ rows, int* __restrict__ deg, int nnz) {
    int tid = blockIdx.x * blockDim.x + threadIdx.x;
    if (tid >= nnz) return;
    atomicAdd(&deg[rows[tid]], 1);
}

// in-place per-block exclusive scan of deg; block totals -> sums[blockIdx]
__global__ void k_scan1(int* __restrict__ deg, int* __restrict__ sums, int n) {
    __shared__ int lds[256];
    int i = blockIdx.x * 256 + threadIdx.x;
    int v = (i < n) ? deg[i] : 0;
    lds[threadIdx.x] = v;
    __syncthreads();
    for (int off = 1; off < 256; off <<= 1) {
        int t = (threadIdx.x >= off) ? lds[threadIdx.x - off] : 0;
        __syncthreads();
        lds[threadIdx.x] += t;
        __syncthreads();
    }
    int inc = lds[threadIdx.x];
    if (i < n) deg[i] = inc - v;               // exclusive within block
    if (threadIdx.x == 255) sums[blockIdx.x] = inc;  // block total
}

// single-block exclusive scan of sums[0..n)
__global__ void k_scan2(int* __restrict__ sums, int n) {
    __shared__ int lds[256];
    __shared__ int carry;
    if (threadIdx.x == 0) carry = 0;
    __syncthreads();
    for (int base = 0; base < n; base += 256) {
        int i = base + threadIdx.x;
        int v = (i < n) ? sums[i] : 0;
        lds[threadIdx.x] = v;
        __syncthreads();
        for (int off = 1; off < 256; off <<= 1) {
            int t = (threadIdx.x >= off) ? lds[threadIdx.x - off] : 0;
            __syncthreads();
            lds[threadIdx.x] += t;
            __syncthreads();
        }
        int inc = lds[threadIdx.x];
        if (i < n) sums[i] = (inc - v) + carry;
        __syncthreads();
        if (threadIdx.x == 255) carry += lds[255];
        __syncthreads();
    }
}

__global__ void k_scan3(const int* __restrict__ deg, const int* __restrict__ sums,
                        int* __restrict__ row_ptr, int* __restrict__ nextp, int nnz) {
    int i = blockIdx.x * blockDim.x + threadIdx.x;
    if (i >= NNODES) return;
    int rp = deg[i] + sums[i >> 8];
    row_ptr[i] = rp;
    nextp[i] = rp;
    if (i == 0) row_ptr[NNODES] = nnz;
}

__global__ void k_scatter(const int* __restrict__ rows, const int* __restrict__ cols,
                          const float* __restrict__ vals, int* __restrict__ nextp,
                          int* __restrict__ pcol, float* __restrict__ pval, int nnz) {
    int e = blockIdx.x * blockDim.x + threadIdx.x;
    if (e >= nnz) return;
    int r = rows[e];
    int p = atomicAdd(&nextp[r], 1);
    pcol[p] = cols[e];
    pval[p] = vals[e];
}

// ---------------------------------------------------------------------------
// CSR SPMM (gather form): 16 threads per row, float4 per thread.
// Each output row written exactly once -> no atomics, no pre-memset.
// ---------------------------------------------------------------------------
__global__ void k_spmm_csr(const int* __restrict__ row_ptr, const int* __restrict__ pcol,
                           const float* __restrict__ pval, const float* __restrict__ x,
                           float* __restrict__ y) {
    int tid = blockIdx.x * blockDim.x + threadIdx.x;
    int r = tid >> 4;
    if (r >= NNODES) return;
    int c4 = (tid & 15) << 2;
    int s = row_ptr[r];
    int e = row_ptr[r + 1];
    float4 acc = make_float4(0.f, 0.f, 0.f, 0.f);
    for (int i = s; i < e; ++i) {
        int col = pcol[i];
        float v = pval[i];
        float4 xv = *(const float4*)(x + (size_t)col * D + c4);
        acc.x += v * xv.x; acc.y += v * xv.y; acc.z += v * xv.z; acc.w += v * xv.w;
    }
    *(float4*)(y + (size_t)r * D + c4) = acc;
}

// ---------------------------------------------------------------------------
// out = (a*out + gather(x)) * s for the 3 light_out outputs
// ---------------------------------------------------------------------------
__global__ void k_gather(const float* __restrict__ x, const int* __restrict__ users,
                         const int* __restrict__ pos, const int* __restrict__ neg,
                         float* __restrict__ out, float a, float s) {
    int tid = blockIdx.x * blockDim.x + threadIdx.x;
    const int per_set = B * (D / 4);
    const int total = 3 * per_set;
    if (tid >= total) return;
    int set = tid / per_set;
    int rem = tid - set * per_set;
    int b   = rem / (D / 4);
    int c4  = (rem % (D / 4)) * 4;
    int node;
    if (set == 0)      node = users[b];
    else if (set == 1) node = N_USERS + pos[b];
    else               node = N_USERS + neg[b];
    float4 g = *(const float4*)(x + (size_t)node * D + c4);
    float* op = out + (size_t)tid * 4;
    float4 o;
    if (a != 0.0f) {
        o = *(const float4*)op;
        o.x = (a * o.x + g.x) * s;
        o.y = (a * o.y + g.y) * s;
        o.z = (a * o.z + g.z) * s;
        o.w = (a * o.w + g.w) * s;
    } else {
        o.x = g.x * s; o.y = g.y * s; o.z = g.z * s; o.w = g.w * s;
    }
    *(float4*)op = o;
}

// ---------------------------------------------------------------------------
// Ego outputs (outputs 3,4,5)
// ---------------------------------------------------------------------------
__global__ void k_ego(const float* __restrict__ ue, const float* __restrict__ ie,
                      const int* __restrict__ um, const int* __restrict__ im,
                      const int* __restrict__ users, const int* __restrict__ pos,
                      const int* __restrict__ neg, float* __restrict__ out) {
    int tid = blockIdx.x * blockDim.x + threadIdx.x;
    const int per_set = B * (D / 4);
    const int total = 3 * per_set;
    if (tid >= total) return;
    int set = tid / per_set;
    int rem = tid - set * per_set;
    int b   = rem / (D / 4);
    int c4  = (rem % (D / 4)) * 4;
    float4 v; int4 m;
    if (set == 0) {
        int n = users[b];
        v = *(const float4*)(ue + (size_t)n * D + c4);
        m = *(const int4*)(um + (size_t)n * D + c4);
    } else if (set == 1) {
        int n = pos[b];
        v = *(const float4*)(ie + (size_t)n * D + c4);
        m = *(const int4*)(im + (size_t)n * D + c4);
    } else {
        int n = neg[b];
        v = *(const float4*)(ie + (size_t)n * D + c4);
        m = *(const int4*)(im + (size_t)n * D + c4);
    }
    v.x *= (float)m.x; v.y *= (float)m.y; v.z *= (float)m.z; v.w *= (float)m.w;
    *(float4*)(out + (size_t)tid * 4) = v;
}

extern "C" void kernel_launch(void* const* d_in, const int* in_sizes, int n_in,
                              void* d_out, int out_size, void* d_ws, size_t ws_size,
                              hipStream_t stream) {
    const float* ue   = (const float*)d_in[0];
    const float* ie   = (const float*)d_in[1];
    const int*   um   = (const int*)d_in[2];
    const int*   im   = (const int*)d_in[3];
    const int*   rows = (const int*)d_in[4];
    const int*   cols = (const int*)d_in[5];
    const float* vals = (const float*)d_in[6];
    const int*   users = (const int*)d_in[7];
    const int*   pos   = (const int*)d_in[8];
    const int*   neg   = (const int*)d_in[9];
    int nnz = in_sizes[4];

    float* out = (float*)d_out;

    // workspace layout
    float* X = (float*)d_ws;                           // NNODES*D floats
    float* Y = X + (size_t)NNODES * D;                 // NNODES*D floats
    int*   deg     = (int*)(Y + (size_t)NNODES * D);   // NNODES (becomes block-exclusive scan)
    int*   row_ptr = deg + NNODES;                     // NNODES+1
    int*   nextp   = row_ptr + NNODES + 1;             // NNODES
    int*   sums    = nextp + NNODES;                   // up to 4096
    int*   pcol    = sums + 4096;                      // nnz
    float* pval    = (float*)(pcol + nnz);             // nnz

    const int blk = 256;
    const int scan_blocks = (NNODES + 255) / 256;      // 2344

    // --- CSR build ---
    hipMemsetAsync(deg, 0, (size_t)NNODES * sizeof(int), stream);
    k_hist<<<(nnz + blk - 1) / blk, blk, 0, stream>>>(rows, deg, nnz);
    k_scan1<<<scan_blocks, 256, 0, stream>>>(deg, sums, NNODES);
    k_scan2<<<1, 256, 0, stream>>>(sums, scan_blocks);
    k_scan3<<<(NNODES + blk - 1) / blk, blk, 0, stream>>>(deg, sums, row_ptr, nextp, nnz);
    k_scatter<<<(nnz + blk - 1) / blk, blk, 0, stream>>>(rows, cols, vals, nextp, pcol, pval, nnz);

    // --- layer-0 embeddings (masked concat) ---
    int n_mask = NNODES * (D / 4);
    k_mask_concat<<<(n_mask + blk - 1) / blk, blk, 0, stream>>>(ue, ie, um, im, X);

    // init output accumulators with layer-0 gathers; fill ego outputs
    int n_g = 3 * B * (D / 4);
    k_gather<<<(n_g + blk - 1) / blk, blk, 0, stream>>>(X, users, pos, neg, out, 0.0f, 1.0f);
    k_ego<<<(n_g + blk - 1) / blk, blk, 0, stream>>>(ue, ie, um, im, users, pos, neg,
                                                     out + (size_t)3 * B * D);

    // --- 3 propagation layers (CSR gather SPMM, no atomics, no memset) ---
    int n_s = NNODES * 16;
    for (int l = 0; l < 3; ++l) {
        k_spmm_csr<<<(n_s + blk - 1) / blk, blk, 0, stream>>>(row_ptr, pcol, pval, X, Y);
        float s = (l == 2) ? 0.25f : 1.0f;
        k_gather<<<(n_g + blk - 1) / blk, blk, 0, stream>>>(Y, users, pos, neg, out, 1.0f, s);
        float* t = X; X = Y; Y = t;
    }
}

// Round 3
// 676.173 us; speedup vs baseline: 5.0586x; 1.1693x over previous
//
#include <hip/hip_runtime.h>

#define N_USERS 400000
#define N_ITEMS 200000
#define NNODES  600000   // N_USERS + N_ITEMS
#define D 64
#define B 8192

// ---------------------------------------------------------------------------
// CSR build: histogram -> dinv -> scan -> scatter (cols only; vals recomputed)
// ---------------------------------------------------------------------------
__global__ void k_hist(const int* __restrict__ rows, int* __restrict__ deg, int nnz) {
    int tid = blockIdx.x * blockDim.x + threadIdx.x;
    if (tid >= nnz) return;
    atomicAdd(&deg[rows[tid]], 1);
}

__global__ void k_dinv(const int* __restrict__ deg, float* __restrict__ dinv) {
    int i = blockIdx.x * blockDim.x + threadIdx.x;
    if (i >= NNODES) return;
    int d = deg[i];
    dinv[i] = (d > 0) ? (float)(1.0 / sqrt((double)d)) : 0.0f;
}

// in-place per-block exclusive scan of deg; block totals -> sums[blockIdx]
__global__ void k_scan1(int* __restrict__ deg, int* __restrict__ sums, int n) {
    __shared__ int lds[256];
    int i = blockIdx.x * 256 + threadIdx.x;
    int v = (i < n) ? deg[i] : 0;
    lds[threadIdx.x] = v;
    __syncthreads();
    for (int off = 1; off < 256; off <<= 1) {
        int t = (threadIdx.x >= off) ? lds[threadIdx.x - off] : 0;
        __syncthreads();
        lds[threadIdx.x] += t;
        __syncthreads();
    }
    int inc = lds[threadIdx.x];
    if (i < n) deg[i] = inc - v;               // exclusive within block
    if (threadIdx.x == 255) sums[blockIdx.x] = inc;  // block total
}

// single-block exclusive scan of sums[0..n)
__global__ void k_scan2(int* __restrict__ sums, int n) {
    __shared__ int lds[256];
    __shared__ int carry;
    if (threadIdx.x == 0) carry = 0;
    __syncthreads();
    for (int base = 0; base < n; base += 256) {
        int i = base + threadIdx.x;
        int v = (i < n) ? sums[i] : 0;
        lds[threadIdx.x] = v;
        __syncthreads();
        for (int off = 1; off < 256; off <<= 1) {
            int t = (threadIdx.x >= off) ? lds[threadIdx.x - off] : 0;
            __syncthreads();
            lds[threadIdx.x] += t;
            __syncthreads();
        }
        int inc = lds[threadIdx.x];
        if (i < n) sums[i] = (inc - v) + carry;
        __syncthreads();
        if (threadIdx.x == 255) carry += lds[255];
        __syncthreads();
    }
}

__global__ void k_scan3(const int* __restrict__ deg, const int* __restrict__ sums,
                        int* __restrict__ row_ptr, int* __restrict__ nextp, int nnz) {
    int i = blockIdx.x * blockDim.x + threadIdx.x;
    if (i >= NNODES) return;
    int rp = deg[i] + sums[i >> 8];
    row_ptr[i] = rp;
    nextp[i] = rp;
    if (i == 0) row_ptr[NNODES] = nnz;
}

__global__ void k_scatter(const int* __restrict__ rows, const int* __restrict__ cols,
                          int* __restrict__ nextp, int* __restrict__ pcol, int nnz) {
    int e = blockIdx.x * blockDim.x + threadIdx.x;
    if (e >= nnz) return;
    int r = rows[e];
    int p = atomicAdd(&nextp[r], 1);
    pcol[p] = cols[e];
}

// ---------------------------------------------------------------------------
// sizes[r] = popcount of prefix mask row (one wave per node)
// ---------------------------------------------------------------------------
__global__ void k_sizes(const int* __restrict__ um, const int* __restrict__ im,
                        int* __restrict__ sizes) {
    int gtid = blockIdx.x * blockDim.x + threadIdx.x;
    int r = gtid >> 6;          // one wave (64 lanes) per node
    int lane = gtid & 63;
    if (r >= NNODES) return;
    int m = (r < N_USERS) ? um[(size_t)r * D + lane]
                          : im[(size_t)(r - N_USERS) * D + lane];
    unsigned long long bal = __ballot(m != 0);
    if (lane == 0) sizes[r] = (int)__popcll(bal);
}

// ---------------------------------------------------------------------------
// Ego outputs (3,4,5) AND layer-0 acc init (0,1,2) — identical values.
// One wave per slot; lane = column.
// ---------------------------------------------------------------------------
__global__ void k_ego_init(const float* __restrict__ ue, const float* __restrict__ ie,
                           const int* __restrict__ sizes,
                           const int* __restrict__ users, const int* __restrict__ pos,
                           const int* __restrict__ neg, float* __restrict__ out) {
    int gtid = blockIdx.x * blockDim.x + threadIdx.x;
    int slot = gtid >> 6;
    int c = gtid & 63;
    if (slot >= 3 * B) return;
    int set = slot / B;
    int b = slot - set * B;
    int node;
    if (set == 0)      node = users[b];
    else if (set == 1) node = N_USERS + pos[b];
    else               node = N_USERS + neg[b];
    float v = (node < N_USERS) ? ue[(size_t)node * D + c]
                               : ie[(size_t)(node - N_USERS) * D + c];
    v *= (c < sizes[node]) ? 1.0f : 0.0f;
    out[(size_t)slot * D + c] = v;                       // acc init (layer-0 term)
    out[(size_t)(3 * B + slot) * D + c] = v;             // ego output
}

// ---------------------------------------------------------------------------
// Layer-1 SPMM: y[r] = sum val * (emb[col] masked by prefix size).
// 16 threads/row, float4/thread, 2-way unrolled for MLP.
// ---------------------------------------------------------------------------
__global__ void k_spmm1(const int* __restrict__ row_ptr, const int* __restrict__ pcol,
                        const float* __restrict__ dinv, const int* __restrict__ sizes,
                        const float* __restrict__ ue, const float* __restrict__ ie,
                        float* __restrict__ y) {
    int tid = blockIdx.x * blockDim.x + threadIdx.x;
    int r = tid >> 4;
    if (r >= NNODES) return;
    int c4 = (tid & 15) << 2;
    int s = row_ptr[r];
    int e = row_ptr[r + 1];
    float dr = dinv[r];
    float4 acc = make_float4(0.f, 0.f, 0.f, 0.f);
    int i = s;
    for (; i + 1 < e; i += 2) {
        int c0 = pcol[i], c1 = pcol[i + 1];
        float v0 = dr * dinv[c0], v1 = dr * dinv[c1];
        int sz0 = sizes[c0], sz1 = sizes[c1];
        const float* p0 = (c0 < N_USERS) ? ue + (size_t)c0 * D : ie + (size_t)(c0 - N_USERS) * D;
        const float* p1 = (c1 < N_USERS) ? ue + (size_t)c1 * D : ie + (size_t)(c1 - N_USERS) * D;
        float4 a0 = *(const float4*)(p0 + c4);
        float4 a1 = *(const float4*)(p1 + c4);
        acc.x += v0 * ((c4 + 0 < sz0) ? a0.x : 0.f) + v1 * ((c4 + 0 < sz1) ? a1.x : 0.f);
        acc.y += v0 * ((c4 + 1 < sz0) ? a0.y : 0.f) + v1 * ((c4 + 1 < sz1) ? a1.y : 0.f);
        acc.z += v0 * ((c4 + 2 < sz0) ? a0.z : 0.f) + v1 * ((c4 + 2 < sz1) ? a1.z : 0.f);
        acc.w += v0 * ((c4 + 3 < sz0) ? a0.w : 0.f) + v1 * ((c4 + 3 < sz1) ? a1.w : 0.f);
    }
    if (i < e) {
        int c0 = pcol[i];
        float v0 = dr * dinv[c0];
        int sz0 = sizes[c0];
        const float* p0 = (c0 < N_USERS) ? ue + (size_t)c0 * D : ie + (size_t)(c0 - N_USERS) * D;
        float4 a0 = *(const float4*)(p0 + c4);
        acc.x += v0 * ((c4 + 0 < sz0) ? a0.x : 0.f);
        acc.y += v0 * ((c4 + 1 < sz0) ? a0.y : 0.f);
        acc.z += v0 * ((c4 + 2 < sz0) ? a0.z : 0.f);
        acc.w += v0 * ((c4 + 3 < sz0) ? a0.w : 0.f);
    }
    *(float4*)(y + (size_t)r * D + c4) = acc;
}

// ---------------------------------------------------------------------------
// Layer-2 SPMM: y[r] = sum val * x[col] (dense x), 2-way unrolled.
// ---------------------------------------------------------------------------
__global__ void k_spmm2(const int* __restrict__ row_ptr, const int* __restrict__ pcol,
                        const float* __restrict__ dinv, const float* __restrict__ x,
                        float* __restrict__ y) {
    int tid = blockIdx.x * blockDim.x + threadIdx.x;
    int r = tid >> 4;
    if (r >= NNODES) return;
    int c4 = (tid & 15) << 2;
    int s = row_ptr[r];
    int e = row_ptr[r + 1];
    float dr = dinv[r];
    float4 acc = make_float4(0.f, 0.f, 0.f, 0.f);
    int i = s;
    for (; i + 1 < e; i += 2) {
        int c0 = pcol[i], c1 = pcol[i + 1];
        float v0 = dr * dinv[c0], v1 = dr * dinv[c1];
        float4 a0 = *(const float4*)(x + (size_t)c0 * D + c4);
        float4 a1 = *(const float4*)(x + (size_t)c1 * D + c4);
        acc.x += v0 * a0.x + v1 * a1.x;
        acc.y += v0 * a0.y + v1 * a1.y;
        acc.z += v0 * a0.z + v1 * a1.z;
        acc.w += v0 * a0.w + v1 * a1.w;
    }
    if (i < e) {
        int c0 = pcol[i];
        float v0 = dr * dinv[c0];
        float4 a0 = *(const float4*)(x + (size_t)c0 * D + c4);
        acc.x += v0 * a0.x;
        acc.y += v0 * a0.y;
        acc.z += v0 * a0.z;
        acc.w += v0 * a0.w;
    }
    *(float4*)(y + (size_t)r * D + c4) = acc;
}

// ---------------------------------------------------------------------------
// Accumulate gathered rows of y into out slots (outputs 0..2): out += y[node]
// ---------------------------------------------------------------------------
__global__ void k_acc(const float* __restrict__ y, const int* __restrict__ users,
                      const int* __restrict__ pos, const int* __restrict__ neg,
                      float* __restrict__ out) {
    int tid = blockIdx.x * blockDim.x + threadIdx.x;
    int slot = tid >> 4;
    if (slot >= 3 * B) return;
    int c4 = (tid & 15) << 2;
    int set = slot / B;
    int b = slot - set * B;
    int node;
    if (set == 0)      node = users[b];
    else if (set == 1) node = N_USERS + pos[b];
    else               node = N_USERS + neg[b];
    float4 g = *(const float4*)(y + (size_t)node * D + c4);
    float* op = out + (size_t)slot * D + c4;
    float4 o = *(const float4*)op;
    o.x += g.x; o.y += g.y; o.z += g.z; o.w += g.w;
    *(float4*)op = o;
}

// ---------------------------------------------------------------------------
// Layer-3 SPMM sampled at the 3*B output rows, fused mean epilogue:
//   out[slot] = (out[slot] + sum val * x[col]) * 0.25
// ---------------------------------------------------------------------------
__global__ void k_spmm3(const int* __restrict__ row_ptr, const int* __restrict__ pcol,
                        const float* __restrict__ dinv, const float* __restrict__ x,
                        const int* __restrict__ users, const int* __restrict__ pos,
                        const int* __restrict__ neg, float* __restrict__ out) {
    int tid = blockIdx.x * blockDim.x + threadIdx.x;
    int slot = tid >> 4;
    if (slot >= 3 * B) return;
    int c4 = (tid & 15) << 2;
    int set = slot / B;
    int b = slot - set * B;
    int r;
    if (set == 0)      r = users[b];
    else if (set == 1) r = N_USERS + pos[b];
    else               r = N_USERS + neg[b];
    int s = row_ptr[r];
    int e = row_ptr[r + 1];
    float dr = dinv[r];
    float4 acc = make_float4(0.f, 0.f, 0.f, 0.f);
    int i = s;
    for (; i + 1 < e; i += 2) {
        int c0 = pcol[i], c1 = pcol[i + 1];
        float v0 = dr * dinv[c0], v1 = dr * dinv[c1];
        float4 a0 = *(const float4*)(x + (size_t)c0 * D + c4);
        float4 a1 = *(const float4*)(x + (size_t)c1 * D + c4);
        acc.x += v0 * a0.x + v1 * a1.x;
        acc.y += v0 * a0.y + v1 * a1.y;
        acc.z += v0 * a0.z + v1 * a1.z;
        acc.w += v0 * a0.w + v1 * a1.w;
    }
    if (i < e) {
        int c0 = pcol[i];
        float v0 = dr * dinv[c0];
        float4 a0 = *(const float4*)(x + (size_t)c0 * D + c4);
        acc.x += v0 * a0.x;
        acc.y += v0 * a0.y;
        acc.z += v0 * a0.z;
        acc.w += v0 * a0.w;
    }
    float* op = out + (size_t)slot * D + c4;
    float4 o = *(const float4*)op;
    o.x = (o.x + acc.x) * 0.25f;
    o.y = (o.y + acc.y) * 0.25f;
    o.z = (o.z + acc.z) * 0.25f;
    o.w = (o.w + acc.w) * 0.25f;
    *(float4*)op = o;
}

extern "C" void kernel_launch(void* const* d_in, const int* in_sizes, int n_in,
                              void* d_out, int out_size, void* d_ws, size_t ws_size,
                              hipStream_t stream) {
    const float* ue   = (const float*)d_in[0];
    const float* ie   = (const float*)d_in[1];
    const int*   um   = (const int*)d_in[2];
    const int*   im   = (const int*)d_in[3];
    const int*   rows = (const int*)d_in[4];
    const int*   cols = (const int*)d_in[5];
    const int*   users = (const int*)d_in[7];
    const int*   pos   = (const int*)d_in[8];
    const int*   neg   = (const int*)d_in[9];
    int nnz = in_sizes[4];

    float* out = (float*)d_out;

    // workspace layout
    float* Y1 = (float*)d_ws;                          // NNODES*D
    float* X2 = Y1 + (size_t)NNODES * D;               // NNODES*D
    int*   deg     = (int*)(X2 + (size_t)NNODES * D);  // NNODES
    int*   row_ptr = deg + NNODES;                     // NNODES+1
    int*   nextp   = row_ptr + NNODES + 1;             // NNODES
    int*   sizes   = nextp + NNODES;                   // NNODES
    int*   sums    = sizes + NNODES;                   // up to 4096
    float* dinv    = (float*)(sums + 4096);            // NNODES
    int*   pcol    = (int*)(dinv + NNODES);            // nnz

    const int blk = 256;
    const int scan_blocks = (NNODES + 255) / 256;      // 2344

    // --- CSR build ---
    hipMemsetAsync(deg, 0, (size_t)NNODES * sizeof(int), stream);
    k_hist<<<(nnz + blk - 1) / blk, blk, 0, stream>>>(rows, deg, nnz);
    k_dinv<<<(NNODES + blk - 1) / blk, blk, 0, stream>>>(deg, dinv);
    k_scan1<<<scan_blocks, 256, 0, stream>>>(deg, sums, NNODES);
    k_scan2<<<1, 256, 0, stream>>>(sums, scan_blocks);
    k_scan3<<<(NNODES + blk - 1) / blk, blk, 0, stream>>>(deg, sums, row_ptr, nextp, nnz);
    k_scatter<<<(nnz + blk - 1) / blk, blk, 0, stream>>>(rows, cols, nextp, pcol, nnz);

    // --- prefix-mask sizes (one wave per node) ---
    k_sizes<<<(NNODES * 64 + blk - 1) / blk, blk, 0, stream>>>(um, im, sizes);

    // --- ego outputs + layer-0 acc init (identical values) ---
    k_ego_init<<<(3 * B * 64 + blk - 1) / blk, blk, 0, stream>>>(ue, ie, sizes,
                                                                 users, pos, neg, out);

    int n_full = NNODES * 16;
    int n_samp = 3 * B * 16;

    // layer 1: Y1 = A * (masked emb); acc += Y1[samples]
    k_spmm1<<<(n_full + blk - 1) / blk, blk, 0, stream>>>(row_ptr, pcol, dinv, sizes, ue, ie, Y1);
    k_acc<<<(n_samp + blk - 1) / blk, blk, 0, stream>>>(Y1, users, pos, neg, out);

    // layer 2: X2 = A * Y1; acc += X2[samples]
    k_spmm2<<<(n_full + blk - 1) / blk, blk, 0, stream>>>(row_ptr, pcol, dinv, Y1, X2);
    k_acc<<<(n_samp + blk - 1) / blk, blk, 0, stream>>>(X2, users, pos, neg, out);

    // layer 3: sampled rows only, fused /4 epilogue
    k_spmm3<<<(n_samp + blk - 1) / blk, blk, 0, stream>>>(row_ptr, pcol, dinv, X2,
                                                          users, pos, neg, out);
}

// Round 5
// 592.180 us; speedup vs baseline: 5.7761x; 1.1418x over previous
//
#include <hip/hip_runtime.h>

#define N_USERS 400000
#define N_ITEMS 200000
#define NNODES  600000   // N_USERS + N_ITEMS
#define D 64
#define B 8192

// ---------------------------------------------------------------------------
// bf16 helpers (manual, no header-API dependence)
// ---------------------------------------------------------------------------
__device__ __forceinline__ float bflo(unsigned u) { return __uint_as_float(u << 16); }
__device__ __forceinline__ float bfhi(unsigned u) { return __uint_as_float(u & 0xffff0000u); }
__device__ __forceinline__ unsigned short f2bf(float f) {   // round-to-nearest-even
    unsigned u = __float_as_uint(f);
    unsigned r = u + 0x7fffu + ((u >> 16) & 1u);
    return (unsigned short)(r >> 16);
}

// acc[0..7] += v * bf16x8(word4)
__device__ __forceinline__ void unpack_fma(float* acc, uint4 wv, float v) {
    acc[0] += v * bflo(wv.x); acc[1] += v * bfhi(wv.x);
    acc[2] += v * bflo(wv.y); acc[3] += v * bfhi(wv.y);
    acc[4] += v * bflo(wv.z); acc[5] += v * bfhi(wv.z);
    acc[6] += v * bflo(wv.w); acc[7] += v * bfhi(wv.w);
}

// ---------------------------------------------------------------------------
// CSR build: histogram -> dinv -> scan -> scatter (cols only; vals recomputed)
// ---------------------------------------------------------------------------
__global__ void k_hist(const int* __restrict__ rows, int* __restrict__ deg, int nnz) {
    int tid = blockIdx.x * blockDim.x + threadIdx.x;
    if (tid >= nnz) return;
    atomicAdd(&deg[rows[tid]], 1);
}

__global__ void k_dinv(const int* __restrict__ deg, float* __restrict__ dinv) {
    int i = blockIdx.x * blockDim.x + threadIdx.x;
    if (i >= NNODES) return;
    int d = deg[i];
    dinv[i] = (d > 0) ? (float)(1.0 / sqrt((double)d)) : 0.0f;
}

__global__ void k_scan1(int* __restrict__ deg, int* __restrict__ sums, int n) {
    __shared__ int lds[256];
    int i = blockIdx.x * 256 + threadIdx.x;
    int v = (i < n) ? deg[i] : 0;
    lds[threadIdx.x] = v;
    __syncthreads();
    for (int off = 1; off < 256; off <<= 1) {
        int t = (threadIdx.x >= off) ? lds[threadIdx.x - off] : 0;
        __syncthreads();
        lds[threadIdx.x] += t;
        __syncthreads();
    }
    int inc = lds[threadIdx.x];
    if (i < n) deg[i] = inc - v;
    if (threadIdx.x == 255) sums[blockIdx.x] = inc;
}

__global__ void k_scan2(int* __restrict__ sums, int n) {
    __shared__ int lds[256];
    __shared__ int carry;
    if (threadIdx.x == 0) carry = 0;
    __syncthreads();
    for (int base = 0; base < n; base += 256) {
        int i = base + threadIdx.x;
        int v = (i < n) ? sums[i] : 0;
        lds[threadIdx.x] = v;
        __syncthreads();
        for (int off = 1; off < 256; off <<= 1) {
            int t = (threadIdx.x >= off) ? lds[threadIdx.x - off] : 0;
            __syncthreads();
            lds[threadIdx.x] += t;
            __syncthreads();
        }
        int inc = lds[threadIdx.x];
        if (i < n) sums[i] = (inc - v) + carry;
        __syncthreads();
        if (threadIdx.x == 255) carry += lds[255];
        __syncthreads();
    }
}

__global__ void k_scan3(const int* __restrict__ deg, const int* __restrict__ sums,
                        int* __restrict__ row_ptr, int* __restrict__ nextp, int nnz) {
    int i = blockIdx.x * blockDim.x + threadIdx.x;
    if (i >= NNODES) return;
    int rp = deg[i] + sums[i >> 8];
    row_ptr[i] = rp;
    nextp[i] = rp;
    if (i == 0) row_ptr[NNODES] = nnz;
}

__global__ void k_scatter(const int* __restrict__ rows, const int* __restrict__ cols,
                          int* __restrict__ nextp, int* __restrict__ pcol, int nnz) {
    int e = blockIdx.x * blockDim.x + threadIdx.x;
    if (e >= nnz) return;
    int r = rows[e];
    int p = atomicAdd(&nextp[r], 1);
    pcol[p] = cols[e];
}

// ---------------------------------------------------------------------------
// Fused: sizes[r] (ballot over mask row) + X0[r] = bf16(masked emb row)
// One wave per node, lane = column.
// ---------------------------------------------------------------------------
__global__ void k_x0(const float* __restrict__ ue, const float* __restrict__ ie,
                     const int* __restrict__ um, const int* __restrict__ im,
                     unsigned short* __restrict__ x0, int* __restrict__ sizes) {
    int gtid = blockIdx.x * blockDim.x + threadIdx.x;
    int r = gtid >> 6;
    int lane = gtid & 63;
    if (r >= NNODES) return;
    int m; float v;
    if (r < N_USERS) {
        m = um[(size_t)r * D + lane];
        v = ue[(size_t)r * D + lane];
    } else {
        int r2 = r - N_USERS;
        m = im[(size_t)r2 * D + lane];
        v = ie[(size_t)r2 * D + lane];
    }
    unsigned long long bal = __ballot(m != 0);
    v = m ? v : 0.0f;
    x0[(size_t)r * D + lane] = f2bf(v);
    if (lane == 0) sizes[r] = (int)__popcll(bal);
}

// ---------------------------------------------------------------------------
// Ego outputs (3,4,5) AND layer-0 acc init (0,1,2) — exact f32.
// ---------------------------------------------------------------------------
__global__ void k_ego_init(const float* __restrict__ ue, const float* __restrict__ ie,
                           const int* __restrict__ sizes,
                           const int* __restrict__ users, const int* __restrict__ pos,
                           const int* __restrict__ neg, float* __restrict__ out) {
    int gtid = blockIdx.x * blockDim.x + threadIdx.x;
    int slot = gtid >> 6;
    int c = gtid & 63;
    if (slot >= 3 * B) return;
    int set = slot / B;
    int b = slot - set * B;
    int node;
    if (set == 0)      node = users[b];
    else if (set == 1) node = N_USERS + pos[b];
    else               node = N_USERS + neg[b];
    float v = (node < N_USERS) ? ue[(size_t)node * D + c]
                               : ie[(size_t)(node - N_USERS) * D + c];
    v *= (c < sizes[node]) ? 1.0f : 0.0f;
    out[(size_t)slot * D + c] = v;
    out[(size_t)(3 * B + slot) * D + c] = v;
}

// ---------------------------------------------------------------------------
// bf16 SPMM: y[r] = sum (dinv[r]*dinv[col]) * x[col]; f32 accumulate.
// 8 threads/row, 8 bf16 (one uint4) per thread. 2-way edge unroll.
// x,y viewed as uint (bf16 pair) arrays: node stride = 32 uints.
// ---------------------------------------------------------------------------
__global__ void k_spmm_bf(const int* __restrict__ row_ptr, const int* __restrict__ pcol,
                          const float* __restrict__ dinv, const unsigned* __restrict__ x,
                          unsigned* __restrict__ y) {
    int tid = blockIdx.x * blockDim.x + threadIdx.x;
    int r = tid >> 3;
    if (r >= NNODES) return;
    int cp = (tid & 7) << 2;           // uint offset within row (4 uints = 8 bf16)
    int s = row_ptr[r];
    int e = row_ptr[r + 1];
    float dr = dinv[r];
    float acc[8] = {0.f, 0.f, 0.f, 0.f, 0.f, 0.f, 0.f, 0.f};
    int i = s;
    for (; i + 1 < e; i += 2) {
        int c0 = pcol[i], c1 = pcol[i + 1];
        float v0 = dr * dinv[c0], v1 = dr * dinv[c1];
        uint4 w0 = *(const uint4*)(x + (size_t)c0 * 32 + cp);
        uint4 w1 = *(const uint4*)(x + (size_t)c1 * 32 + cp);
        unpack_fma(acc, w0, v0);
        unpack_fma(acc, w1, v1);
    }
    if (i < e) {
        int c0 = pcol[i];
        float v0 = dr * dinv[c0];
        uint4 w0 = *(const uint4*)(x + (size_t)c0 * 32 + cp);
        unpack_fma(acc, w0, v0);
    }
    uint4 o;
    o.x = (unsigned)f2bf(acc[0]) | ((unsigned)f2bf(acc[1]) << 16);
    o.y = (unsigned)f2bf(acc[2]) | ((unsigned)f2bf(acc[3]) << 16);
    o.z = (unsigned)f2bf(acc[4]) | ((unsigned)f2bf(acc[5]) << 16);
    o.w = (unsigned)f2bf(acc[6]) | ((unsigned)f2bf(acc[7]) << 16);
    *(uint4*)(y + (size_t)r * 32 + cp) = o;
}

// ---------------------------------------------------------------------------
// out[slot] += y_bf16[node]   (outputs 0..2)
// ---------------------------------------------------------------------------
__global__ void k_acc_bf(const unsigned* __restrict__ y, const int* __restrict__ users,
                         const int* __restrict__ pos, const int* __restrict__ neg,
                         float* __restrict__ out) {
    int tid = blockIdx.x * blockDim.x + threadIdx.x;
    int slot = tid >> 3;
    if (slot >= 3 * B) return;
    int cp = (tid & 7) << 2;
    int set = slot / B;
    int b = slot - set * B;
    int node;
    if (set == 0)      node = users[b];
    else if (set == 1) node = N_USERS + pos[b];
    else               node = N_USERS + neg[b];
    uint4 g = *(const uint4*)(y + (size_t)node * 32 + cp);
    float* op = out + (size_t)slot * D + cp * 2;
    float4 oa = *(const float4*)op;
    float4 ob = *(const float4*)(op + 4);
    oa.x += bflo(g.x); oa.y += bfhi(g.x); oa.z += bflo(g.y); oa.w += bfhi(g.y);
    ob.x += bflo(g.z); ob.y += bfhi(g.z); ob.z += bflo(g.w); ob.w += bfhi(g.w);
    *(float4*)op = oa;
    *(float4*)(op + 4) = ob;
}

// ---------------------------------------------------------------------------
// Layer-3 SPMM sampled at the 3*B output rows, fused mean epilogue:
//   out[slot] = (out[slot] + sum val * x_bf16[col]) * 0.25
// ---------------------------------------------------------------------------
__global__ void k_spmm3_bf(const int* __restrict__ row_ptr, const int* __restrict__ pcol,
                           const float* __restrict__ dinv, const unsigned* __restrict__ x,
                           const int* __restrict__ users, const int* __restrict__ pos,
                           const int* __restrict__ neg, float* __restrict__ out) {
    int tid = blockIdx.x * blockDim.x + threadIdx.x;
    int slot = tid >> 3;
    if (slot >= 3 * B) return;
    int cp = (tid & 7) << 2;
    int set = slot / B;
    int b = slot - set * B;
    int r;
    if (set == 0)      r = users[b];
    else if (set == 1) r = N_USERS + pos[b];
    else               r = N_USERS + neg[b];
    int s = row_ptr[r];
    int e = row_ptr[r + 1];
    float dr = dinv[r];
    float acc[8] = {0.f, 0.f, 0.f, 0.f, 0.f, 0.f, 0.f, 0.f};
    int i = s;
    for (; i + 1 < e; i += 2) {
        int c0 = pcol[i], c1 = pcol[i + 1];
        float v0 = dr * dinv[c0], v1 = dr * dinv[c1];
        uint4 w0 = *(const uint4*)(x + (size_t)c0 * 32 + cp);
        uint4 w1 = *(const uint4*)(x + (size_t)c1 * 32 + cp);
        unpack_fma(acc, w0, v0);
        unpack_fma(acc, w1, v1);
    }
    if (i < e) {
        int c0 = pcol[i];
        float v0 = dr * dinv[c0];
        uint4 w0 = *(const uint4*)(x + (size_t)c0 * 32 + cp);
        unpack_fma(acc, w0, v0);
    }
    float* op = out + (size_t)slot * D + cp * 2;
    float4 oa = *(const float4*)op;
    float4 ob = *(const float4*)(op + 4);
    oa.x = (oa.x + acc[0]) * 0.25f; oa.y = (oa.y + acc[1]) * 0.25f;
    oa.z = (oa.z + acc[2]) * 0.25f; oa.w = (oa.w + acc[3]) * 0.25f;
    ob.x = (ob.x + acc[4]) * 0.25f; ob.y = (ob.y + acc[5]) * 0.25f;
    ob.z = (ob.z + acc[6]) * 0.25f; ob.w = (ob.w + acc[7]) * 0.25f;
    *(float4*)op = oa;
    *(float4*)(op + 4) = ob;
}

extern "C" void kernel_launch(void* const* d_in, const int* in_sizes, int n_in,
                              void* d_out, int out_size, void* d_ws, size_t ws_size,
                              hipStream_t stream) {
    const float* ue   = (const float*)d_in[0];
    const float* ie   = (const float*)d_in[1];
    const int*   um   = (const int*)d_in[2];
    const int*   im   = (const int*)d_in[3];
    const int*   rows = (const int*)d_in[4];
    const int*   cols = (const int*)d_in[5];
    const int*   users = (const int*)d_in[7];
    const int*   pos   = (const int*)d_in[8];
    const int*   neg   = (const int*)d_in[9];
    int nnz = in_sizes[4];

    float* out = (float*)d_out;

    // workspace layout (bf16 node buffers first, 16B aligned)
    unsigned short* X0 = (unsigned short*)d_ws;         // NNODES*D bf16
    unsigned short* Y1 = X0 + (size_t)NNODES * D;       // NNODES*D bf16
    unsigned short* X2 = Y1 + (size_t)NNODES * D;       // NNODES*D bf16
    int*   deg     = (int*)(X2 + (size_t)NNODES * D);   // NNODES
    int*   row_ptr = deg + NNODES;                      // NNODES+1
    int*   nextp   = row_ptr + NNODES + 1;              // NNODES
    int*   sizes   = nextp + NNODES;                    // NNODES
    int*   sums    = sizes + NNODES;                    // up to 4096
    float* dinv    = (float*)(sums + 4096);             // NNODES
    int*   pcol    = (int*)(dinv + NNODES);             // nnz

    const int blk = 256;
    const int scan_blocks = (NNODES + 255) / 256;       // 2344

    // --- CSR build ---
    hipMemsetAsync(deg, 0, (size_t)NNODES * sizeof(int), stream);
    k_hist<<<(nnz + blk - 1) / blk, blk, 0, stream>>>(rows, deg, nnz);
    k_dinv<<<(NNODES + blk - 1) / blk, blk, 0, stream>>>(deg, dinv);
    k_scan1<<<scan_blocks, 256, 0, stream>>>(deg, sums, NNODES);
    k_scan2<<<1, 256, 0, stream>>>(sums, scan_blocks);
    k_scan3<<<(NNODES + blk - 1) / blk, blk, 0, stream>>>(deg, sums, row_ptr, nextp, nnz);
    k_scatter<<<(nnz + blk - 1) / blk, blk, 0, stream>>>(rows, cols, nextp, pcol, nnz);

    // --- fused sizes + masked bf16 X0 ---
    k_x0<<<(NNODES * 64 + blk - 1) / blk, blk, 0, stream>>>(ue, ie, um, im, X0, sizes);

    // --- ego outputs + layer-0 acc init (exact f32) ---
    k_ego_init<<<(3 * B * 64 + blk - 1) / blk, blk, 0, stream>>>(ue, ie, sizes,
                                                                 users, pos, neg, out);

    int n_full = NNODES * 8;
    int n_samp = 3 * B * 8;

    // layer 1: Y1 = A * X0; acc += Y1[samples]
    k_spmm_bf<<<(n_full + blk - 1) / blk, blk, 0, stream>>>(row_ptr, pcol, dinv,
                                                            (const unsigned*)X0, (unsigned*)Y1);
    k_acc_bf<<<(n_samp + blk - 1) / blk, blk, 0, stream>>>((const unsigned*)Y1, users, pos, neg, out);

    // layer 2: X2 = A * Y1; acc += X2[samples]
    k_spmm_bf<<<(n_full + blk - 1) / blk, blk, 0, stream>>>(row_ptr, pcol, dinv,
                                                            (const unsigned*)Y1, (unsigned*)X2);
    k_acc_bf<<<(n_samp + blk - 1) / blk, blk, 0, stream>>>((const unsigned*)X2, users, pos, neg, out);

    // layer 3: sampled rows only, fused /4 epilogue
    k_spmm3_bf<<<(n_samp + blk - 1) / blk, blk, 0, stream>>>(row_ptr, pcol, dinv,
                                                             (const unsigned*)X2,
                                                             users, pos, neg, out);
}

// Round 6
// 580.178 us; speedup vs baseline: 5.8955x; 1.0207x over previous
//
#include <hip/hip_runtime.h>

#define N_USERS 400000
#define N_ITEMS 200000
#define NNODES  600000   // N_USERS + N_ITEMS
#define D 64
#define B 8192

// ---------------------------------------------------------------------------
// bf16 helpers
// ---------------------------------------------------------------------------
__device__ __forceinline__ float bflo(unsigned u) { return __uint_as_float(u << 16); }
__device__ __forceinline__ float bfhi(unsigned u) { return __uint_as_float(u & 0xffff0000u); }
__device__ __forceinline__ unsigned f2bf(float f) {   // round-to-nearest-even
    unsigned u = __float_as_uint(f);
    unsigned r = u + 0x7fffu + ((u >> 16) & 1u);
    return r >> 16;
}

// acc[0..7] += v * bf16x8(word4)
__device__ __forceinline__ void unpack_fma(float* acc, uint4 wv, float v) {
    acc[0] += v * bflo(wv.x); acc[1] += v * bfhi(wv.x);
    acc[2] += v * bflo(wv.y); acc[3] += v * bfhi(wv.y);
    acc[4] += v * bflo(wv.z); acc[5] += v * bfhi(wv.z);
    acc[6] += v * bflo(wv.w); acc[7] += v * bfhi(wv.w);
}

// ---------------------------------------------------------------------------
// CSR build
// ---------------------------------------------------------------------------
__global__ void k_hist(const int* __restrict__ rows, int* __restrict__ deg, int nnz) {
    int tid = blockIdx.x * blockDim.x + threadIdx.x;
    if (tid >= nnz) return;
    atomicAdd(&deg[rows[tid]], 1);
}

// exclusive per-block scan of deg (in place) + block totals + dinv (fused)
__global__ void k_scan1(int* __restrict__ deg, int* __restrict__ sums,
                        float* __restrict__ dinv, int n) {
    __shared__ int lds[256];
    int i = blockIdx.x * 256 + threadIdx.x;
    int v = (i < n) ? deg[i] : 0;
    if (i < n) dinv[i] = (v > 0) ? (float)(1.0 / sqrt((double)v)) : 0.0f;
    lds[threadIdx.x] = v;
    __syncthreads();
    for (int off = 1; off < 256; off <<= 1) {
        int t = (threadIdx.x >= off) ? lds[threadIdx.x - off] : 0;
        __syncthreads();
        lds[threadIdx.x] += t;
        __syncthreads();
    }
    int inc = lds[threadIdx.x];
    if (i < n) deg[i] = inc - v;
    if (threadIdx.x == 255) sums[blockIdx.x] = inc;
}

// single-block (1024 threads) exclusive scan of sums[0..n)
__global__ void k_scan2(int* __restrict__ sums, int n) {
    __shared__ int lds[1024];
    __shared__ int carry;
    if (threadIdx.x == 0) carry = 0;
    __syncthreads();
    for (int base = 0; base < n; base += 1024) {
        int i = base + threadIdx.x;
        int v = (i < n) ? sums[i] : 0;
        lds[threadIdx.x] = v;
        __syncthreads();
        for (int off = 1; off < 1024; off <<= 1) {
            int t = (threadIdx.x >= off) ? lds[threadIdx.x - off] : 0;
            __syncthreads();
            lds[threadIdx.x] += t;
            __syncthreads();
        }
        int inc = lds[threadIdx.x];
        if (i < n) sums[i] = (inc - v) + carry;
        __syncthreads();
        if (threadIdx.x == 1023) carry += lds[1023];
        __syncthreads();
    }
}

__global__ void k_scan3(const int* __restrict__ deg, const int* __restrict__ sums,
                        int* __restrict__ row_ptr, int* __restrict__ nextp, int nnz) {
    int i = blockIdx.x * blockDim.x + threadIdx.x;
    if (i >= NNODES) return;
    int rp = deg[i] + sums[i >> 8];
    row_ptr[i] = rp;
    nextp[i] = rp;
    if (i == 0) row_ptr[NNODES] = nnz;
}

__global__ void k_scatter(const int* __restrict__ rows, const int* __restrict__ cols,
                          int* __restrict__ nextp, int* __restrict__ pcol, int nnz) {
    int e = blockIdx.x * blockDim.x + threadIdx.x;
    if (e >= nnz) return;
    int r = rows[e];
    int p = atomicAdd(&nextp[r], 1);
    pcol[p] = cols[e];
}

// ---------------------------------------------------------------------------
// Fused sizes + bf16 X0, vectorized: 8 threads/row x 8 cols.
// float4 x2 + int4 x2 loads, uint4 store; shfl-reduce for sizes.
// ---------------------------------------------------------------------------
__global__ void k_x0(const float* __restrict__ ue, const float* __restrict__ ie,
                     const int* __restrict__ um, const int* __restrict__ im,
                     unsigned short* __restrict__ x0, int* __restrict__ sizes) {
    int tid = blockIdx.x * blockDim.x + threadIdx.x;
    int r = tid >> 3;
    if (r >= NNODES) return;
    int c8 = (tid & 7) << 3;
    const float* ep; const int* mp;
    if (r < N_USERS) {
        ep = ue + (size_t)r * D + c8;
        mp = um + (size_t)r * D + c8;
    } else {
        int r2 = r - N_USERS;
        ep = ie + (size_t)r2 * D + c8;
        mp = im + (size_t)r2 * D + c8;
    }
    float4 e0 = *(const float4*)ep;
    float4 e1 = *(const float4*)(ep + 4);
    int4 m0 = *(const int4*)mp;
    int4 m1 = *(const int4*)(mp + 4);
    int cnt = (m0.x != 0) + (m0.y != 0) + (m0.z != 0) + (m0.w != 0)
            + (m1.x != 0) + (m1.y != 0) + (m1.z != 0) + (m1.w != 0);
    float v0 = m0.x ? e0.x : 0.f, v1 = m0.y ? e0.y : 0.f;
    float v2 = m0.z ? e0.z : 0.f, v3 = m0.w ? e0.w : 0.f;
    float v4 = m1.x ? e1.x : 0.f, v5 = m1.y ? e1.y : 0.f;
    float v6 = m1.z ? e1.z : 0.f, v7 = m1.w ? e1.w : 0.f;
    uint4 o;
    o.x = f2bf(v0) | (f2bf(v1) << 16);
    o.y = f2bf(v2) | (f2bf(v3) << 16);
    o.z = f2bf(v4) | (f2bf(v5) << 16);
    o.w = f2bf(v6) | (f2bf(v7) << 16);
    *(uint4*)(x0 + (size_t)r * D + c8) = o;
    cnt += __shfl_xor(cnt, 1);
    cnt += __shfl_xor(cnt, 2);
    cnt += __shfl_xor(cnt, 4);
    if ((tid & 7) == 0) sizes[r] = cnt;
}

// ---------------------------------------------------------------------------
// Ego outputs (3,4,5) AND layer-0 acc init (0,1,2) — exact f32, vectorized.
// 8 threads/slot x 8 cols.
// ---------------------------------------------------------------------------
__global__ void k_ego_init(const float* __restrict__ ue, const float* __restrict__ ie,
                           const int* __restrict__ sizes,
                           const int* __restrict__ users, const int* __restrict__ pos,
                           const int* __restrict__ neg, float* __restrict__ out) {
    int tid = blockIdx.x * blockDim.x + threadIdx.x;
    int slot = tid >> 3;
    if (slot >= 3 * B) return;
    int c8 = (tid & 7) << 3;
    int set = slot / B;
    int b = slot - set * B;
    int node;
    if (set == 0)      node = users[b];
    else if (set == 1) node = N_USERS + pos[b];
    else               node = N_USERS + neg[b];
    const float* ep = ((node < N_USERS) ? ue + (size_t)node * D
                                        : ie + (size_t)(node - N_USERS) * D) + c8;
    float4 e0 = *(const float4*)ep;
    float4 e1 = *(const float4*)(ep + 4);
    int sz = sizes[node];
    e0.x = (c8 + 0 < sz) ? e0.x : 0.f; e0.y = (c8 + 1 < sz) ? e0.y : 0.f;
    e0.z = (c8 + 2 < sz) ? e0.z : 0.f; e0.w = (c8 + 3 < sz) ? e0.w : 0.f;
    e1.x = (c8 + 4 < sz) ? e1.x : 0.f; e1.y = (c8 + 5 < sz) ? e1.y : 0.f;
    e1.z = (c8 + 6 < sz) ? e1.z : 0.f; e1.w = (c8 + 7 < sz) ? e1.w : 0.f;
    float* o0 = out + (size_t)slot * D + c8;
    float* o1 = out + (size_t)(3 * B + slot) * D + c8;
    *(float4*)o0 = e0; *(float4*)(o0 + 4) = e1;
    *(float4*)o1 = e0; *(float4*)(o1 + 4) = e1;
}

// ---------------------------------------------------------------------------
// bf16 SPMM: y[r] = sum (dinv[r]*dinv[col]) * x[col]; f32 accumulate.
// 8 threads/row, 8 bf16 (one uint4) per thread.
// ---------------------------------------------------------------------------
__global__ void k_spmm_bf(const int* __restrict__ row_ptr, const int* __restrict__ pcol,
                          const float* __restrict__ dinv, const unsigned* __restrict__ x,
                          unsigned* __restrict__ y) {
    int tid = blockIdx.x * blockDim.x + threadIdx.x;
    int r = tid >> 3;
    if (r >= NNODES) return;
    int cp = (tid & 7) << 2;
    int s = row_ptr[r];
    int e = row_ptr[r + 1];
    float dr = dinv[r];
    float acc[8] = {0.f, 0.f, 0.f, 0.f, 0.f, 0.f, 0.f, 0.f};
    int i = s;
    for (; i + 1 < e; i += 2) {
        int c0 = pcol[i], c1 = pcol[i + 1];
        float v0 = dr * dinv[c0], v1 = dr * dinv[c1];
        uint4 w0 = *(const uint4*)(x + (size_t)c0 * 32 + cp);
        uint4 w1 = *(const uint4*)(x + (size_t)c1 * 32 + cp);
        unpack_fma(acc, w0, v0);
        unpack_fma(acc, w1, v1);
    }
    if (i < e) {
        int c0 = pcol[i];
        float v0 = dr * dinv[c0];
        uint4 w0 = *(const uint4*)(x + (size_t)c0 * 32 + cp);
        unpack_fma(acc, w0, v0);
    }
    uint4 o;
    o.x = f2bf(acc[0]) | (f2bf(acc[1]) << 16);
    o.y = f2bf(acc[2]) | (f2bf(acc[3]) << 16);
    o.z = f2bf(acc[4]) | (f2bf(acc[5]) << 16);
    o.w = f2bf(acc[6]) | (f2bf(acc[7]) << 16);
    *(uint4*)(y + (size_t)r * 32 + cp) = o;
}

// ---------------------------------------------------------------------------
// out[slot] += y_bf16[node]   (outputs 0..2)
// ---------------------------------------------------------------------------
__global__ void k_acc_bf(const unsigned* __restrict__ y, const int* __restrict__ users,
                         const int* __restrict__ pos, const int* __restrict__ neg,
                         float* __restrict__ out) {
    int tid = blockIdx.x * blockDim.x + threadIdx.x;
    int slot = tid >> 3;
    if (slot >= 3 * B) return;
    int cp = (tid & 7) << 2;
    int set = slot / B;
    int b = slot - set * B;
    int node;
    if (set == 0)      node = users[b];
    else if (set == 1) node = N_USERS + pos[b];
    else               node = N_USERS + neg[b];
    uint4 g = *(const uint4*)(y + (size_t)node * 32 + cp);
    float* op = out + (size_t)slot * D + cp * 2;
    float4 oa = *(const float4*)op;
    float4 ob = *(const float4*)(op + 4);
    oa.x += bflo(g.x); oa.y += bfhi(g.x); oa.z += bflo(g.y); oa.w += bfhi(g.y);
    ob.x += bflo(g.z); ob.y += bfhi(g.z); ob.z += bflo(g.w); ob.w += bfhi(g.w);
    *(float4*)op = oa;
    *(float4*)(op + 4) = ob;
}

// ---------------------------------------------------------------------------
// Layer-3 sampled SPMM, fused with X2 sample-accumulate and mean epilogue:
//   out[slot] = (out[slot] + x[r] + sum val * x[col]) * 0.25
// ---------------------------------------------------------------------------
__global__ void k_spmm3_bf(const int* __restrict__ row_ptr, const int* __restrict__ pcol,
                           const float* __restrict__ dinv, const unsigned* __restrict__ x,
                           const int* __restrict__ users, const int* __restrict__ pos,
                           const int* __restrict__ neg, float* __restrict__ out) {
    int tid = blockIdx.x * blockDim.x + threadIdx.x;
    int slot = tid >> 3;
    if (slot >= 3 * B) return;
    int cp = (tid & 7) << 2;
    int set = slot / B;
    int b = slot - set * B;
    int r;
    if (set == 0)      r = users[b];
    else if (set == 1) r = N_USERS + pos[b];
    else               r = N_USERS + neg[b];
    int s = row_ptr[r];
    int e = row_ptr[r + 1];
    float dr = dinv[r];
    float acc[8] = {0.f, 0.f, 0.f, 0.f, 0.f, 0.f, 0.f, 0.f};
    // self row (layer-2 accumulate term), weight 1
    uint4 gs = *(const uint4*)(x + (size_t)r * 32 + cp);
    unpack_fma(acc, gs, 1.0f);
    int i = s;
    for (; i + 1 < e; i += 2) {
        int c0 = pcol[i], c1 = pcol[i + 1];
        float v0 = dr * dinv[c0], v1 = dr * dinv[c1];
        uint4 w0 = *(const uint4*)(x + (size_t)c0 * 32 + cp);
        uint4 w1 = *(const uint4*)(x + (size_t)c1 * 32 + cp);
        unpack_fma(acc, w0, v0);
        unpack_fma(acc, w1, v1);
    }
    if (i < e) {
        int c0 = pcol[i];
        float v0 = dr * dinv[c0];
        uint4 w0 = *(const uint4*)(x + (size_t)c0 * 32 + cp);
        unpack_fma(acc, w0, v0);
    }
    float* op = out + (size_t)slot * D + cp * 2;
    float4 oa = *(const float4*)op;
    float4 ob = *(const float4*)(op + 4);
    oa.x = (oa.x + acc[0]) * 0.25f; oa.y = (oa.y + acc[1]) * 0.25f;
    oa.z = (oa.z + acc[2]) * 0.25f; oa.w = (oa.w + acc[3]) * 0.25f;
    ob.x = (ob.x + acc[4]) * 0.25f; ob.y = (ob.y + acc[5]) * 0.25f;
    ob.z = (ob.z + acc[6]) * 0.25f; ob.w = (ob.w + acc[7]) * 0.25f;
    *(float4*)op = oa;
    *(float4*)(op + 4) = ob;
}

extern "C" void kernel_launch(void* const* d_in, const int* in_sizes, int n_in,
                              void* d_out, int out_size, void* d_ws, size_t ws_size,
                              hipStream_t stream) {
    const float* ue   = (const float*)d_in[0];
    const float* ie   = (const float*)d_in[1];
    const int*   um   = (const int*)d_in[2];
    const int*   im   = (const int*)d_in[3];
    const int*   rows = (const int*)d_in[4];
    const int*   cols = (const int*)d_in[5];
    const int*   users = (const int*)d_in[7];
    const int*   pos   = (const int*)d_in[8];
    const int*   neg   = (const int*)d_in[9];
    int nnz = in_sizes[4];

    float* out = (float*)d_out;

    // workspace layout (bf16 node buffers first, 16B aligned)
    unsigned short* X0 = (unsigned short*)d_ws;         // NNODES*D bf16
    unsigned short* Y1 = X0 + (size_t)NNODES * D;       // NNODES*D bf16
    unsigned short* X2 = Y1 + (size_t)NNODES * D;       // NNODES*D bf16
    int*   deg     = (int*)(X2 + (size_t)NNODES * D);   // NNODES
    int*   row_ptr = deg + NNODES;                      // NNODES+1
    int*   nextp   = row_ptr + NNODES + 1;              // NNODES
    int*   sizes   = nextp + NNODES;                    // NNODES
    int*   sums    = sizes + NNODES;                    // up to 4096
    float* dinv    = (float*)(sums + 4096);             // NNODES
    int*   pcol    = (int*)(dinv + NNODES);             // nnz

    const int blk = 256;
    const int scan_blocks = (NNODES + 255) / 256;       // 2344

    // --- CSR build ---
    hipMemsetAsync(deg, 0, (size_t)NNODES * sizeof(int), stream);
    k_hist<<<(nnz + blk - 1) / blk, blk, 0, stream>>>(rows, deg, nnz);
    k_scan1<<<scan_blocks, 256, 0, stream>>>(deg, sums, dinv, NNODES);
    k_scan2<<<1, 1024, 0, stream>>>(sums, scan_blocks);
    k_scan3<<<(NNODES + blk - 1) / blk, blk, 0, stream>>>(deg, sums, row_ptr, nextp, nnz);
    k_scatter<<<(nnz + blk - 1) / blk, blk, 0, stream>>>(rows, cols, nextp, pcol, nnz);

    // --- fused sizes + masked bf16 X0 (vectorized) ---
    k_x0<<<(NNODES * 8 + blk - 1) / blk, blk, 0, stream>>>(ue, ie, um, im, X0, sizes);

    // --- ego outputs + layer-0 acc init (vectorized) ---
    k_ego_init<<<(3 * B * 8 + blk - 1) / blk, blk, 0, stream>>>(ue, ie, sizes,
                                                                users, pos, neg, out);

    int n_full = NNODES * 8;
    int n_samp = 3 * B * 8;

    // layer 1: Y1 = A * X0; acc += Y1[samples]
    k_spmm_bf<<<(n_full + blk - 1) / blk, blk, 0, stream>>>(row_ptr, pcol, dinv,
                                                            (const unsigned*)X0, (unsigned*)Y1);
    k_acc_bf<<<(n_samp + blk - 1) / blk, blk, 0, stream>>>((const unsigned*)Y1, users, pos, neg, out);

    // layer 2: X2 = A * Y1
    k_spmm_bf<<<(n_full + blk - 1) / blk, blk, 0, stream>>>(row_ptr, pcol, dinv,
                                                            (const unsigned*)Y1, (unsigned*)X2);

    // layer 3: sampled rows only, fused X2-accumulate + /4 epilogue
    k_spmm3_bf<<<(n_samp + blk - 1) / blk, blk, 0, stream>>>(row_ptr, pcol, dinv,
                                                             (const unsigned*)X2,
                                                             users, pos, neg, out);
}

// Round 7
// 575.602 us; speedup vs baseline: 5.9424x; 1.0080x over previous
//
#include <hip/hip_runtime.h>

#define N_USERS 400000
#define N_ITEMS 200000
#define NNODES  600000   // N_USERS + N_ITEMS
#define D 64
#define B 8192

// ---------------------------------------------------------------------------
// bf16 helpers
// ---------------------------------------------------------------------------
__device__ __forceinline__ float bflo(unsigned u) { return __uint_as_float(u << 16); }
__device__ __forceinline__ float bfhi(unsigned u) { return __uint_as_float(u & 0xffff0000u); }
__device__ __forceinline__ unsigned f2bf(float f) {   // round-to-nearest-even
    unsigned u = __float_as_uint(f);
    unsigned r = u + 0x7fffu + ((u >> 16) & 1u);
    return r >> 16;
}

// acc[0..7] += v * bf16x8(word4)
__device__ __forceinline__ void unpack_fma(float* acc, uint4 wv, float v) {
    acc[0] += v * bflo(wv.x); acc[1] += v * bfhi(wv.x);
    acc[2] += v * bflo(wv.y); acc[3] += v * bfhi(wv.y);
    acc[4] += v * bflo(wv.z); acc[5] += v * bfhi(wv.z);
    acc[6] += v * bflo(wv.w); acc[7] += v * bfhi(wv.w);
}

// ---------------------------------------------------------------------------
// CSR build
// ---------------------------------------------------------------------------
__global__ void k_hist(const int* __restrict__ rows, int* __restrict__ deg, int nnz) {
    int tid = blockIdx.x * blockDim.x + threadIdx.x;
    if (tid >= nnz) return;
    atomicAdd(&deg[rows[tid]], 1);
}

// exclusive per-block scan of deg (in place) + block totals + dinv (fused)
__global__ void k_scan1(int* __restrict__ deg, int* __restrict__ sums,
                        float* __restrict__ dinv, int n) {
    __shared__ int lds[256];
    int i = blockIdx.x * 256 + threadIdx.x;
    int v = (i < n) ? deg[i] : 0;
    if (i < n) dinv[i] = (v > 0) ? (float)(1.0 / sqrt((double)v)) : 0.0f;
    lds[threadIdx.x] = v;
    __syncthreads();
    for (int off = 1; off < 256; off <<= 1) {
        int t = (threadIdx.x >= off) ? lds[threadIdx.x - off] : 0;
        __syncthreads();
        lds[threadIdx.x] += t;
        __syncthreads();
    }
    int inc = lds[threadIdx.x];
    if (i < n) deg[i] = inc - v;
    if (threadIdx.x == 255) sums[blockIdx.x] = inc;
}

// single-block (1024 threads) exclusive scan of sums[0..n)
__global__ void k_scan2(int* __restrict__ sums, int n) {
    __shared__ int lds[1024];
    __shared__ int carry;
    if (threadIdx.x == 0) carry = 0;
    __syncthreads();
    for (int base = 0; base < n; base += 1024) {
        int i = base + threadIdx.x;
        int v = (i < n) ? sums[i] : 0;
        lds[threadIdx.x] = v;
        __syncthreads();
        for (int off = 1; off < 1024; off <<= 1) {
            int t = (threadIdx.x >= off) ? lds[threadIdx.x - off] : 0;
            __syncthreads();
            lds[threadIdx.x] += t;
            __syncthreads();
        }
        int inc = lds[threadIdx.x];
        if (i < n) sums[i] = (inc - v) + carry;
        __syncthreads();
        if (threadIdx.x == 1023) carry += lds[1023];
        __syncthreads();
    }
}

__global__ void k_scan3(const int* __restrict__ deg, const int* __restrict__ sums,
                        int* __restrict__ row_ptr, int* __restrict__ nextp, int nnz) {
    int i = blockIdx.x * blockDim.x + threadIdx.x;
    if (i >= NNODES) return;
    int rp = deg[i] + sums[i >> 8];
    row_ptr[i] = rp;
    nextp[i] = rp;
    if (i == 0) row_ptr[NNODES] = nnz;
}

__global__ void k_scatter(const int* __restrict__ rows, const int* __restrict__ cols,
                          int* __restrict__ nextp, int* __restrict__ pcol, int nnz) {
    int e = blockIdx.x * blockDim.x + threadIdx.x;
    if (e >= nnz) return;
    int r = rows[e];
    int p = atomicAdd(&nextp[r], 1);
    pcol[p] = cols[e];
}

// ---------------------------------------------------------------------------
// Pure streaming masked bf16 X0: 4 threads/row x 16 cols.
// 4 float4 + 4 int4 loads, 2 uint4 stores per thread. No shfl, no sizes.
// ---------------------------------------------------------------------------
__global__ void k_x0(const float* __restrict__ ue, const float* __restrict__ ie,
                     const int* __restrict__ um, const int* __restrict__ im,
                     unsigned short* __restrict__ x0) {
    int tid = blockIdx.x * blockDim.x + threadIdx.x;
    int r = tid >> 2;
    if (r >= NNODES) return;
    int c16 = (tid & 3) << 4;
    const float* ep; const int* mp;
    if (r < N_USERS) {
        ep = ue + (size_t)r * D + c16;
        mp = um + (size_t)r * D + c16;
    } else {
        int r2 = r - N_USERS;
        ep = ie + (size_t)r2 * D + c16;
        mp = im + (size_t)r2 * D + c16;
    }
    float4 e0 = *(const float4*)ep;
    float4 e1 = *(const float4*)(ep + 4);
    float4 e2 = *(const float4*)(ep + 8);
    float4 e3 = *(const float4*)(ep + 12);
    int4 m0 = *(const int4*)mp;
    int4 m1 = *(const int4*)(mp + 4);
    int4 m2 = *(const int4*)(mp + 8);
    int4 m3 = *(const int4*)(mp + 12);
    uint4 oa, ob;
    oa.x = f2bf(m0.x ? e0.x : 0.f) | (f2bf(m0.y ? e0.y : 0.f) << 16);
    oa.y = f2bf(m0.z ? e0.z : 0.f) | (f2bf(m0.w ? e0.w : 0.f) << 16);
    oa.z = f2bf(m1.x ? e1.x : 0.f) | (f2bf(m1.y ? e1.y : 0.f) << 16);
    oa.w = f2bf(m1.z ? e1.z : 0.f) | (f2bf(m1.w ? e1.w : 0.f) << 16);
    ob.x = f2bf(m2.x ? e2.x : 0.f) | (f2bf(m2.y ? e2.y : 0.f) << 16);
    ob.y = f2bf(m2.z ? e2.z : 0.f) | (f2bf(m2.w ? e2.w : 0.f) << 16);
    ob.z = f2bf(m3.x ? e3.x : 0.f) | (f2bf(m3.y ? e3.y : 0.f) << 16);
    ob.w = f2bf(m3.z ? e3.z : 0.f) | (f2bf(m3.w ? e3.w : 0.f) << 16);
    unsigned short* op = x0 + (size_t)r * D + c16;
    *(uint4*)op = oa;
    *(uint4*)(op + 8) = ob;
}

// ---------------------------------------------------------------------------
// Ego outputs (3,4,5) AND layer-0 acc init (0,1,2) from bf16 X0 (masked).
// 8 threads/slot x 8 cols.
// ---------------------------------------------------------------------------
__global__ void k_ego_init(const unsigned* __restrict__ x0,
                           const int* __restrict__ users, const int* __restrict__ pos,
                           const int* __restrict__ neg, float* __restrict__ out) {
    int tid = blockIdx.x * blockDim.x + threadIdx.x;
    int slot = tid >> 3;
    if (slot >= 3 * B) return;
    int cp = (tid & 7) << 2;
    int set = slot / B;
    int b = slot - set * B;
    int node;
    if (set == 0)      node = users[b];
    else if (set == 1) node = N_USERS + pos[b];
    else               node = N_USERS + neg[b];
    uint4 g = *(const uint4*)(x0 + (size_t)node * 32 + cp);
    float4 oa, ob;
    oa.x = bflo(g.x); oa.y = bfhi(g.x); oa.z = bflo(g.y); oa.w = bfhi(g.y);
    ob.x = bflo(g.z); ob.y = bfhi(g.z); ob.z = bflo(g.w); ob.w = bfhi(g.w);
    float* o0 = out + (size_t)slot * D + cp * 2;
    float* o1 = out + (size_t)(3 * B + slot) * D + cp * 2;
    *(float4*)o0 = oa; *(float4*)(o0 + 4) = ob;
    *(float4*)o1 = oa; *(float4*)(o1 + 4) = ob;
}

// ---------------------------------------------------------------------------
// bf16 SPMM: y[r] = sum (dinv[r]*dinv[col]) * x[col]; f32 accumulate.
// 8 threads/row, 8 bf16 (one uint4) per thread.
// ---------------------------------------------------------------------------
__global__ void k_spmm_bf(const int* __restrict__ row_ptr, const int* __restrict__ pcol,
                          const float* __restrict__ dinv, const unsigned* __restrict__ x,
                          unsigned* __restrict__ y) {
    int tid = blockIdx.x * blockDim.x + threadIdx.x;
    int r = tid >> 3;
    if (r >= NNODES) return;
    int cp = (tid & 7) << 2;
    int s = row_ptr[r];
    int e = row_ptr[r + 1];
    float dr = dinv[r];
    float acc[8] = {0.f, 0.f, 0.f, 0.f, 0.f, 0.f, 0.f, 0.f};
    int i = s;
    for (; i + 1 < e; i += 2) {
        int c0 = pcol[i], c1 = pcol[i + 1];
        float v0 = dr * dinv[c0], v1 = dr * dinv[c1];
        uint4 w0 = *(const uint4*)(x + (size_t)c0 * 32 + cp);
        uint4 w1 = *(const uint4*)(x + (size_t)c1 * 32 + cp);
        unpack_fma(acc, w0, v0);
        unpack_fma(acc, w1, v1);
    }
    if (i < e) {
        int c0 = pcol[i];
        float v0 = dr * dinv[c0];
        uint4 w0 = *(const uint4*)(x + (size_t)c0 * 32 + cp);
        unpack_fma(acc, w0, v0);
    }
    uint4 o;
    o.x = f2bf(acc[0]) | (f2bf(acc[1]) << 16);
    o.y = f2bf(acc[2]) | (f2bf(acc[3]) << 16);
    o.z = f2bf(acc[4]) | (f2bf(acc[5]) << 16);
    o.w = f2bf(acc[6]) | (f2bf(acc[7]) << 16);
    *(uint4*)(y + (size_t)r * 32 + cp) = o;
}

// ---------------------------------------------------------------------------
// Layer-3 sampled SPMM, fused with Y1 & X2 sample-accumulate + mean epilogue:
//   out[slot] = (out[slot] + y1[r] + x2[r] + sum val * x2[col]) * 0.25
// ---------------------------------------------------------------------------
__global__ void k_spmm3_bf(const int* __restrict__ row_ptr, const int* __restrict__ pcol,
                           const float* __restrict__ dinv,
                           const unsigned* __restrict__ y1, const unsigned* __restrict__ x2,
                           const int* __restrict__ users, const int* __restrict__ pos,
                           const int* __restrict__ neg, float* __restrict__ out) {
    int tid = blockIdx.x * blockDim.x + threadIdx.x;
    int slot = tid >> 3;
    if (slot >= 3 * B) return;
    int cp = (tid & 7) << 2;
    int set = slot / B;
    int b = slot - set * B;
    int r;
    if (set == 0)      r = users[b];
    else if (set == 1) r = N_USERS + pos[b];
    else               r = N_USERS + neg[b];
    int s = row_ptr[r];
    int e = row_ptr[r + 1];
    float dr = dinv[r];
    float acc[8] = {0.f, 0.f, 0.f, 0.f, 0.f, 0.f, 0.f, 0.f};
    uint4 g1 = *(const uint4*)(y1 + (size_t)r * 32 + cp);
    uint4 g2 = *(const uint4*)(x2 + (size_t)r * 32 + cp);
    unpack_fma(acc, g1, 1.0f);
    unpack_fma(acc, g2, 1.0f);
    int i = s;
    for (; i + 1 < e; i += 2) {
        int c0 = pcol[i], c1 = pcol[i + 1];
        float v0 = dr * dinv[c0], v1 = dr * dinv[c1];
        uint4 w0 = *(const uint4*)(x2 + (size_t)c0 * 32 + cp);
        uint4 w1 = *(const uint4*)(x2 + (size_t)c1 * 32 + cp);
        unpack_fma(acc, w0, v0);
        unpack_fma(acc, w1, v1);
    }
    if (i < e) {
        int c0 = pcol[i];
        float v0 = dr * dinv[c0];
        uint4 w0 = *(const uint4*)(x2 + (size_t)c0 * 32 + cp);
        unpack_fma(acc, w0, v0);
    }
    float* op = out + (size_t)slot * D + cp * 2;
    float4 oa = *(const float4*)op;
    float4 ob = *(const float4*)(op + 4);
    oa.x = (oa.x + acc[0]) * 0.25f; oa.y = (oa.y + acc[1]) * 0.25f;
    oa.z = (oa.z + acc[2]) * 0.25f; oa.w = (oa.w + acc[3]) * 0.25f;
    ob.x = (ob.x + acc[4]) * 0.25f; ob.y = (ob.y + acc[5]) * 0.25f;
    ob.z = (ob.z + acc[6]) * 0.25f; ob.w = (ob.w + acc[7]) * 0.25f;
    *(float4*)op = oa;
    *(float4*)(op + 4) = ob;
}

extern "C" void kernel_launch(void* const* d_in, const int* in_sizes, int n_in,
                              void* d_out, int out_size, void* d_ws, size_t ws_size,
                              hipStream_t stream) {
    const float* ue   = (const float*)d_in[0];
    const float* ie   = (const float*)d_in[1];
    const int*   um   = (const int*)d_in[2];
    const int*   im   = (const int*)d_in[3];
    const int*   rows = (const int*)d_in[4];
    const int*   cols = (const int*)d_in[5];
    const int*   users = (const int*)d_in[7];
    const int*   pos   = (const int*)d_in[8];
    const int*   neg   = (const int*)d_in[9];
    int nnz = in_sizes[4];

    float* out = (float*)d_out;

    // workspace layout (bf16 node buffers first, 16B aligned)
    unsigned short* X0 = (unsigned short*)d_ws;         // NNODES*D bf16
    unsigned short* Y1 = X0 + (size_t)NNODES * D;       // NNODES*D bf16
    unsigned short* X2 = Y1 + (size_t)NNODES * D;       // NNODES*D bf16
    int*   deg     = (int*)(X2 + (size_t)NNODES * D);   // NNODES
    int*   row_ptr = deg + NNODES;                      // NNODES+1
    int*   nextp   = row_ptr + NNODES + 1;              // NNODES
    int*   sums    = nextp + NNODES;                    // up to 4096
    float* dinv    = (float*)(sums + 4096);             // NNODES
    int*   pcol    = (int*)(dinv + NNODES);             // nnz

    const int blk = 256;
    const int scan_blocks = (NNODES + 255) / 256;       // 2344

    // --- CSR build ---
    hipMemsetAsync(deg, 0, (size_t)NNODES * sizeof(int), stream);
    k_hist<<<(nnz + blk - 1) / blk, blk, 0, stream>>>(rows, deg, nnz);
    k_scan1<<<scan_blocks, 256, 0, stream>>>(deg, sums, dinv, NNODES);
    k_scan2<<<1, 1024, 0, stream>>>(sums, scan_blocks);
    k_scan3<<<(NNODES + blk - 1) / blk, blk, 0, stream>>>(deg, sums, row_ptr, nextp, nnz);
    k_scatter<<<(nnz + blk - 1) / blk, blk, 0, stream>>>(rows, cols, nextp, pcol, nnz);

    // --- masked bf16 X0 (pure streaming) ---
    k_x0<<<(NNODES * 4 + blk - 1) / blk, blk, 0, stream>>>(ue, ie, um, im, X0);

    // --- ego outputs + layer-0 acc init from X0 ---
    k_ego_init<<<(3 * B * 8 + blk - 1) / blk, blk, 0, stream>>>((const unsigned*)X0,
                                                                users, pos, neg, out);

    int n_full = NNODES * 8;
    int n_samp = 3 * B * 8;

    // layer 1: Y1 = A * X0
    k_spmm_bf<<<(n_full + blk - 1) / blk, blk, 0, stream>>>(row_ptr, pcol, dinv,
                                                            (const unsigned*)X0, (unsigned*)Y1);

    // layer 2: X2 = A * Y1
    k_spmm_bf<<<(n_full + blk - 1) / blk, blk, 0, stream>>>(row_ptr, pcol, dinv,
                                                            (const unsigned*)Y1, (unsigned*)X2);

    // layer 3: sampled rows, fused Y1+X2 accumulate + /4 epilogue
    k_spmm3_bf<<<(n_samp + blk - 1) / blk, blk, 0, stream>>>(row_ptr, pcol, dinv,
                                                             (const unsigned*)Y1,
                                                             (const unsigned*)X2,
                                                             users, pos, neg, out);
}

// Round 8
// 567.951 us; speedup vs baseline: 6.0225x; 1.0135x over previous
//
#include <hip/hip_runtime.h>

#define N_USERS 400000
#define N_ITEMS 200000
#define NNODES  600000   // N_USERS + N_ITEMS
#define D 64
#define B 8192

// ---------------------------------------------------------------------------
// bf16 helpers
// ---------------------------------------------------------------------------
__device__ __forceinline__ float bflo(unsigned u) { return __uint_as_float(u << 16); }
__device__ __forceinline__ float bfhi(unsigned u) { return __uint_as_float(u & 0xffff0000u); }
__device__ __forceinline__ unsigned f2bf(float f) {   // round-to-nearest-even
    unsigned u = __float_as_uint(f);
    unsigned r = u + 0x7fffu + ((u >> 16) & 1u);
    return r >> 16;
}

// acc[0..7] += v * bf16x8(word4)
__device__ __forceinline__ void unpack_fma(float* acc, uint4 wv, float v) {
    acc[0] += v * bflo(wv.x); acc[1] += v * bfhi(wv.x);
    acc[2] += v * bflo(wv.y); acc[3] += v * bfhi(wv.y);
    acc[4] += v * bflo(wv.z); acc[5] += v * bfhi(wv.z);
    acc[6] += v * bflo(wv.w); acc[7] += v * bfhi(wv.w);
}

// ---------------------------------------------------------------------------
// CSR build
// ---------------------------------------------------------------------------
__global__ void k_hist(const int* __restrict__ rows, int* __restrict__ deg, int nnz) {
    int tid = blockIdx.x * blockDim.x + threadIdx.x;
    if (tid >= nnz) return;
    atomicAdd(&deg[rows[tid]], 1);
}

// exclusive per-block scan of deg (in place) + block totals + dinv (fused)
__global__ void k_scan1(int* __restrict__ deg, int* __restrict__ sums,
                        float* __restrict__ dinv, int n) {
    __shared__ int lds[256];
    int i = blockIdx.x * 256 + threadIdx.x;
    int v = (i < n) ? deg[i] : 0;
    if (i < n) dinv[i] = (v > 0) ? (float)(1.0 / sqrt((double)v)) : 0.0f;
    lds[threadIdx.x] = v;
    __syncthreads();
    for (int off = 1; off < 256; off <<= 1) {
        int t = (threadIdx.x >= off) ? lds[threadIdx.x - off] : 0;
        __syncthreads();
        lds[threadIdx.x] += t;
        __syncthreads();
    }
    int inc = lds[threadIdx.x];
    if (i < n) deg[i] = inc - v;
    if (threadIdx.x == 255) sums[blockIdx.x] = inc;
}

// single-block (1024 threads) exclusive scan of sums[0..n)
__global__ void k_scan2(int* __restrict__ sums, int n) {
    __shared__ int lds[1024];
    __shared__ int carry;
    if (threadIdx.x == 0) carry = 0;
    __syncthreads();
    for (int base = 0; base < n; base += 1024) {
        int i = base + threadIdx.x;
        int v = (i < n) ? sums[i] : 0;
        lds[threadIdx.x] = v;
        __syncthreads();
        for (int off = 1; off < 1024; off <<= 1) {
            int t = (threadIdx.x >= off) ? lds[threadIdx.x - off] : 0;
            __syncthreads();
            lds[threadIdx.x] += t;
            __syncthreads();
        }
        int inc = lds[threadIdx.x];
        if (i < n) sums[i] = (inc - v) + carry;
        __syncthreads();
        if (threadIdx.x == 1023) carry += lds[1023];
        __syncthreads();
    }
}

__global__ void k_scan3(const int* __restrict__ deg, const int* __restrict__ sums,
                        int* __restrict__ row_ptr, int* __restrict__ nextp, int nnz) {
    int i = blockIdx.x * blockDim.x + threadIdx.x;
    if (i >= NNODES) return;
    int rp = deg[i] + sums[i >> 8];
    row_ptr[i] = rp;
    nextp[i] = rp;
    if (i == 0) row_ptr[NNODES] = nnz;
}

__global__ void k_scatter(const int* __restrict__ rows, const int* __restrict__ cols,
                          int* __restrict__ nextp, int* __restrict__ pcol, int nnz) {
    int e = blockIdx.x * blockDim.x + threadIdx.x;
    if (e >= nnz) return;
    int r = rows[e];
    int p = atomicAdd(&nextp[r], 1);
    pcol[p] = cols[e];
}

// ---------------------------------------------------------------------------
// Masked bf16 X0 — flat elementwise, perfectly coalesced.
// Thread handles 4 f32-quads at grid stride; lane l loads quad base+l, so
// each load instruction covers 1 KB contiguous, each store 512 B contiguous.
// ---------------------------------------------------------------------------
#define X0_THREADS (NNODES * 4)   // total quads / 4 per thread
__global__ void k_x0(const float* __restrict__ ue, const float* __restrict__ ie,
                     const int* __restrict__ um, const int* __restrict__ im,
                     unsigned* __restrict__ x0) {
    int tid = blockIdx.x * blockDim.x + threadIdx.x;
    if (tid >= X0_THREADS) return;
    const int QU = N_USERS * (D / 4);   // user-region quads (6.4M)
    #pragma unroll
    for (int k = 0; k < 4; ++k) {
        int q = tid + k * X0_THREADS;
        const float4* ep; const int4* mp;
        if (q < QU) {
            ep = (const float4*)ue + q;
            mp = (const int4*)um + q;
        } else {
            ep = (const float4*)ie + (q - QU);
            mp = (const int4*)im + (q - QU);
        }
        float4 e = *ep;
        int4 m = *mp;
        uint2 o;
        o.x = f2bf(m.x ? e.x : 0.f) | (f2bf(m.y ? e.y : 0.f) << 16);
        o.y = f2bf(m.z ? e.z : 0.f) | (f2bf(m.w ? e.w : 0.f) << 16);
        ((uint2*)x0)[q] = o;
    }
}

// ---------------------------------------------------------------------------
// bf16 SPMM: y[r] = sum (dinv[r]*dinv[col]) * x[col]; f32 accumulate.
// 8 threads/row, 8 bf16 (one uint4) per thread.
// ---------------------------------------------------------------------------
__global__ void k_spmm_bf(const int* __restrict__ row_ptr, const int* __restrict__ pcol,
                          const float* __restrict__ dinv, const unsigned* __restrict__ x,
                          unsigned* __restrict__ y) {
    int tid = blockIdx.x * blockDim.x + threadIdx.x;
    int r = tid >> 3;
    if (r >= NNODES) return;
    int cp = (tid & 7) << 2;
    int s = row_ptr[r];
    int e = row_ptr[r + 1];
    float dr = dinv[r];
    float acc[8] = {0.f, 0.f, 0.f, 0.f, 0.f, 0.f, 0.f, 0.f};
    int i = s;
    for (; i + 1 < e; i += 2) {
        int c0 = pcol[i], c1 = pcol[i + 1];
        float v0 = dr * dinv[c0], v1 = dr * dinv[c1];
        uint4 w0 = *(const uint4*)(x + (size_t)c0 * 32 + cp);
        uint4 w1 = *(const uint4*)(x + (size_t)c1 * 32 + cp);
        unpack_fma(acc, w0, v0);
        unpack_fma(acc, w1, v1);
    }
    if (i < e) {
        int c0 = pcol[i];
        float v0 = dr * dinv[c0];
        uint4 w0 = *(const uint4*)(x + (size_t)c0 * 32 + cp);
        unpack_fma(acc, w0, v0);
    }
    uint4 o;
    o.x = f2bf(acc[0]) | (f2bf(acc[1]) << 16);
    o.y = f2bf(acc[2]) | (f2bf(acc[3]) << 16);
    o.z = f2bf(acc[4]) | (f2bf(acc[5]) << 16);
    o.w = f2bf(acc[6]) | (f2bf(acc[7]) << 16);
    *(uint4*)(y + (size_t)r * 32 + cp) = o;
}

// ---------------------------------------------------------------------------
// Layer-3 sampled SPMM with everything fused:
//   out[slot]       = (x0[r] + y1[r] + x2[r] + sum val * x2[col]) * 0.25
//   out[3B + slot]  = x0[r]            (ego output)
// No read-modify of out; single writer.
// ---------------------------------------------------------------------------
__global__ void k_spmm3_bf(const int* __restrict__ row_ptr, const int* __restrict__ pcol,
                           const float* __restrict__ dinv,
                           const unsigned* __restrict__ x0, const unsigned* __restrict__ y1,
                           const unsigned* __restrict__ x2,
                           const int* __restrict__ users, const int* __restrict__ pos,
                           const int* __restrict__ neg, float* __restrict__ out) {
    int tid = blockIdx.x * blockDim.x + threadIdx.x;
    int slot = tid >> 3;
    if (slot >= 3 * B) return;
    int cp = (tid & 7) << 2;
    int set = slot / B;
    int b = slot - set * B;
    int r;
    if (set == 0)      r = users[b];
    else if (set == 1) r = N_USERS + pos[b];
    else               r = N_USERS + neg[b];
    int s = row_ptr[r];
    int e = row_ptr[r + 1];
    float dr = dinv[r];
    float acc[8] = {0.f, 0.f, 0.f, 0.f, 0.f, 0.f, 0.f, 0.f};
    uint4 g0 = *(const uint4*)(x0 + (size_t)r * 32 + cp);
    uint4 g1 = *(const uint4*)(y1 + (size_t)r * 32 + cp);
    uint4 g2 = *(const uint4*)(x2 + (size_t)r * 32 + cp);
    unpack_fma(acc, g1, 1.0f);
    unpack_fma(acc, g2, 1.0f);
    int i = s;
    for (; i + 1 < e; i += 2) {
        int c0 = pcol[i], c1 = pcol[i + 1];
        float v0 = dr * dinv[c0], v1 = dr * dinv[c1];
        uint4 w0 = *(const uint4*)(x2 + (size_t)c0 * 32 + cp);
        uint4 w1 = *(const uint4*)(x2 + (size_t)c1 * 32 + cp);
        unpack_fma(acc, w0, v0);
        unpack_fma(acc, w1, v1);
    }
    if (i < e) {
        int c0 = pcol[i];
        float v0 = dr * dinv[c0];
        uint4 w0 = *(const uint4*)(x2 + (size_t)c0 * 32 + cp);
        unpack_fma(acc, w0, v0);
    }
    // ego values (x0 row) in f32
    float eg[8];
    eg[0] = bflo(g0.x); eg[1] = bfhi(g0.x); eg[2] = bflo(g0.y); eg[3] = bfhi(g0.y);
    eg[4] = bflo(g0.z); eg[5] = bfhi(g0.z); eg[6] = bflo(g0.w); eg[7] = bfhi(g0.w);
    float4 oa, ob;
    oa.x = (eg[0] + acc[0]) * 0.25f; oa.y = (eg[1] + acc[1]) * 0.25f;
    oa.z = (eg[2] + acc[2]) * 0.25f; oa.w = (eg[3] + acc[3]) * 0.25f;
    ob.x = (eg[4] + acc[4]) * 0.25f; ob.y = (eg[5] + acc[5]) * 0.25f;
    ob.z = (eg[6] + acc[6]) * 0.25f; ob.w = (eg[7] + acc[7]) * 0.25f;
    float* o0 = out + (size_t)slot * D + cp * 2;
    float* o1 = out + (size_t)(3 * B + slot) * D + cp * 2;
    *(float4*)o0 = oa;
    *(float4*)(o0 + 4) = ob;
    *(float4*)o1 = make_float4(eg[0], eg[1], eg[2], eg[3]);
    *(float4*)(o1 + 4) = make_float4(eg[4], eg[5], eg[6], eg[7]);
}

extern "C" void kernel_launch(void* const* d_in, const int* in_sizes, int n_in,
                              void* d_out, int out_size, void* d_ws, size_t ws_size,
                              hipStream_t stream) {
    const float* ue   = (const float*)d_in[0];
    const float* ie   = (const float*)d_in[1];
    const int*   um   = (const int*)d_in[2];
    const int*   im   = (const int*)d_in[3];
    const int*   rows = (const int*)d_in[4];
    const int*   cols = (const int*)d_in[5];
    const int*   users = (const int*)d_in[7];
    const int*   pos   = (const int*)d_in[8];
    const int*   neg   = (const int*)d_in[9];
    int nnz = in_sizes[4];

    float* out = (float*)d_out;

    // workspace layout (bf16 node buffers first, 16B aligned)
    unsigned short* X0 = (unsigned short*)d_ws;         // NNODES*D bf16
    unsigned short* Y1 = X0 + (size_t)NNODES * D;       // NNODES*D bf16
    unsigned short* X2 = Y1 + (size_t)NNODES * D;       // NNODES*D bf16
    int*   deg     = (int*)(X2 + (size_t)NNODES * D);   // NNODES
    int*   row_ptr = deg + NNODES;                      // NNODES+1
    int*   nextp   = row_ptr + NNODES + 1;              // NNODES
    int*   sums    = nextp + NNODES;                    // up to 4096
    float* dinv    = (float*)(sums + 4096);             // NNODES
    int*   pcol    = (int*)(dinv + NNODES);             // nnz

    const int blk = 256;
    const int scan_blocks = (NNODES + 255) / 256;       // 2344

    // --- CSR build ---
    hipMemsetAsync(deg, 0, (size_t)NNODES * sizeof(int), stream);
    k_hist<<<(nnz + blk - 1) / blk, blk, 0, stream>>>(rows, deg, nnz);
    k_scan1<<<scan_blocks, 256, 0, stream>>>(deg, sums, dinv, NNODES);
    k_scan2<<<1, 1024, 0, stream>>>(sums, scan_blocks);
    k_scan3<<<(NNODES + blk - 1) / blk, blk, 0, stream>>>(deg, sums, row_ptr, nextp, nnz);
    k_scatter<<<(nnz + blk - 1) / blk, blk, 0, stream>>>(rows, cols, nextp, pcol, nnz);

    // --- masked bf16 X0 (flat, fully coalesced) ---
    k_x0<<<(X0_THREADS + blk - 1) / blk, blk, 0, stream>>>(ue, ie, um, im, (unsigned*)X0);

    int n_full = NNODES * 8;
    int n_samp = 3 * B * 8;

    // layer 1: Y1 = A * X0
    k_spmm_bf<<<(n_full + blk - 1) / blk, blk, 0, stream>>>(row_ptr, pcol, dinv,
                                                            (const unsigned*)X0, (unsigned*)Y1);

    // layer 2: X2 = A * Y1
    k_spmm_bf<<<(n_full + blk - 1) / blk, blk, 0, stream>>>(row_ptr, pcol, dinv,
                                                            (const unsigned*)Y1, (unsigned*)X2);

    // layer 3: sampled rows, fused x0/y1/x2 accumulate + ego + /4 epilogue
    k_spmm3_bf<<<(n_samp + blk - 1) / blk, blk, 0, stream>>>(row_ptr, pcol, dinv,
                                                             (const unsigned*)X0,
                                                             (const unsigned*)Y1,
                                                             (const unsigned*)X2,
                                                             users, pos, neg, out);
}

// Round 9
// 558.981 us; speedup vs baseline: 6.1191x; 1.0160x over previous
//
#include <hip/hip_runtime.h>

#define N_USERS 400000
#define N_ITEMS 200000
#define NNODES  600000   // N_USERS + N_ITEMS
#define D 64
#define B 8192

// ---------------------------------------------------------------------------
// bf16 helpers
// ---------------------------------------------------------------------------
__device__ __forceinline__ float bflo(unsigned u) { return __uint_as_float(u << 16); }
__device__ __forceinline__ float bfhi(unsigned u) { return __uint_as_float(u & 0xffff0000u); }
__device__ __forceinline__ unsigned f2bf(float f) {   // round-to-nearest-even
    unsigned u = __float_as_uint(f);
    unsigned r = u + 0x7fffu + ((u >> 16) & 1u);
    return r >> 16;
}

// acc[0..7] += v * bf16x8(word4)
__device__ __forceinline__ void unpack_fma(float* acc, uint4 wv, float v) {
    acc[0] += v * bflo(wv.x); acc[1] += v * bfhi(wv.x);
    acc[2] += v * bflo(wv.y); acc[3] += v * bfhi(wv.y);
    acc[4] += v * bflo(wv.z); acc[5] += v * bfhi(wv.z);
    acc[6] += v * bflo(wv.w); acc[7] += v * bfhi(wv.w);
}

// ---------------------------------------------------------------------------
// CSR build
// ---------------------------------------------------------------------------
__global__ void k_hist(const int* __restrict__ rows, int* __restrict__ deg, int nnz) {
    int tid = blockIdx.x * blockDim.x + threadIdx.x;
    if (tid >= nnz) return;
    atomicAdd(&deg[rows[tid]], 1);
}

// exclusive per-block scan of deg (in place) + block totals + dinv (fused)
__global__ void k_scan1(int* __restrict__ deg, int* __restrict__ sums,
                        float* __restrict__ dinv, int n) {
    __shared__ int lds[256];
    int i = blockIdx.x * 256 + threadIdx.x;
    int v = (i < n) ? deg[i] : 0;
    if (i < n) dinv[i] = (v > 0) ? (float)(1.0 / sqrt((double)v)) : 0.0f;
    lds[threadIdx.x] = v;
    __syncthreads();
    for (int off = 1; off < 256; off <<= 1) {
        int t = (threadIdx.x >= off) ? lds[threadIdx.x - off] : 0;
        __syncthreads();
        lds[threadIdx.x] += t;
        __syncthreads();
    }
    int inc = lds[threadIdx.x];
    if (i < n) deg[i] = inc - v;
    if (threadIdx.x == 255) sums[blockIdx.x] = inc;
}

// single-block (1024 threads) exclusive scan of sums[0..n)
__global__ void k_scan2(int* __restrict__ sums, int n) {
    __shared__ int lds[1024];
    __shared__ int carry;
    if (threadIdx.x == 0) carry = 0;
    __syncthreads();
    for (int base = 0; base < n; base += 1024) {
        int i = base + threadIdx.x;
        int v = (i < n) ? sums[i] : 0;
        lds[threadIdx.x] = v;
        __syncthreads();
        for (int off = 1; off < 1024; off <<= 1) {
            int t = (threadIdx.x >= off) ? lds[threadIdx.x - off] : 0;
            __syncthreads();
            lds[threadIdx.x] += t;
            __syncthreads();
        }
        int inc = lds[threadIdx.x];
        if (i < n) sums[i] = (inc - v) + carry;
        __syncthreads();
        if (threadIdx.x == 1023) carry += lds[1023];
        __syncthreads();
    }
}

__global__ void k_scan3(const int* __restrict__ deg, const int* __restrict__ sums,
                        int* __restrict__ row_ptr, int* __restrict__ nextp, int nnz) {
    int i = blockIdx.x * blockDim.x + threadIdx.x;
    if (i >= NNODES) return;
    int rp = deg[i] + sums[i >> 8];
    row_ptr[i] = rp;
    nextp[i] = rp;
    if (i == 0) row_ptr[NNODES] = nnz;
}

__global__ void k_scatter(const int* __restrict__ rows, const int* __restrict__ cols,
                          int* __restrict__ nextp, int* __restrict__ pcol, int nnz) {
    int e = blockIdx.x * blockDim.x + threadIdx.x;
    if (e >= nnz) return;
    int r = rows[e];
    int p = atomicAdd(&nextp[r], 1);
    pcol[p] = cols[e];
}

// ---------------------------------------------------------------------------
// sizes[r] = popcount of prefix-mask row. One wave per node, lane = column.
// Only pass that touches the 153.6 MB masks.
// ---------------------------------------------------------------------------
__global__ void k_sizes(const int* __restrict__ um, const int* __restrict__ im,
                        int* __restrict__ sizes) {
    int gtid = blockIdx.x * blockDim.x + threadIdx.x;
    int r = gtid >> 6;
    int lane = gtid & 63;
    if (r >= NNODES) return;
    int m = (r < N_USERS) ? um[(size_t)r * D + lane]
                          : im[(size_t)(r - N_USERS) * D + lane];
    unsigned long long bal = __ballot(m != 0);
    if (lane == 0) sizes[r] = (int)__popcll(bal);
}

// ---------------------------------------------------------------------------
// Frontier marking.
// k_mark_s: per sample row r: flag2[r]=flag1[r]=1; flag2[col]=1 for its cols.
// k_mark_1: per row with flag2 set: flag1[col]=1 for its cols.
// ---------------------------------------------------------------------------
__global__ void k_mark_s(const int* __restrict__ row_ptr, const int* __restrict__ pcol,
                         const int* __restrict__ users, const int* __restrict__ pos,
                         const int* __restrict__ neg,
                         char* __restrict__ flag1, char* __restrict__ flag2) {
    int slot = blockIdx.x * blockDim.x + threadIdx.x;
    if (slot >= 3 * B) return;
    int set = slot / B;
    int b = slot - set * B;
    int r;
    if (set == 0)      r = users[b];
    else if (set == 1) r = N_USERS + pos[b];
    else               r = N_USERS + neg[b];
    flag2[r] = 1;
    flag1[r] = 1;
    int e = row_ptr[r + 1];
    for (int i = row_ptr[r]; i < e; ++i) flag2[pcol[i]] = 1;
}

__global__ void k_mark_1(const int* __restrict__ row_ptr, const int* __restrict__ pcol,
                         const char* __restrict__ flag2, char* __restrict__ flag1) {
    int r = blockIdx.x * blockDim.x + threadIdx.x;
    if (r >= NNODES) return;
    if (!flag2[r]) return;
    int e = row_ptr[r + 1];
    for (int i = row_ptr[r]; i < e; ++i) flag1[pcol[i]] = 1;
}

// ---------------------------------------------------------------------------
// Layer-1 SPMM from RAW f32 embeddings with inline prefix-mask:
//   y1[r] = sum dinv[r]*dinv[c] * (emb[c] masked to sizes[c]),  flag1 rows only.
// 8 threads/row, 8 f32 cols each, bf16 output.
// ---------------------------------------------------------------------------
__global__ void k_spmm1(const int* __restrict__ row_ptr, const int* __restrict__ pcol,
                        const float* __restrict__ dinv, const int* __restrict__ sizes,
                        const char* __restrict__ flag1,
                        const float* __restrict__ ue, const float* __restrict__ ie,
                        unsigned* __restrict__ y1) {
    int tid = blockIdx.x * blockDim.x + threadIdx.x;
    int r = tid >> 3;
    if (r >= NNODES) return;
    if (!flag1[r]) return;
    int c8 = (tid & 7) << 3;          // f32 col base
    int s = row_ptr[r];
    int e = row_ptr[r + 1];
    float dr = dinv[r];
    float acc[8] = {0.f, 0.f, 0.f, 0.f, 0.f, 0.f, 0.f, 0.f};
    for (int i = s; i < e; ++i) {
        int c = pcol[i];
        float v = dr * dinv[c];
        int sz = sizes[c];
        const float* p = ((c < N_USERS) ? ue + (size_t)c * D
                                        : ie + (size_t)(c - N_USERS) * D) + c8;
        float4 e0 = *(const float4*)p;
        float4 e1 = *(const float4*)(p + 4);
        acc[0] += v * ((c8 + 0 < sz) ? e0.x : 0.f);
        acc[1] += v * ((c8 + 1 < sz) ? e0.y : 0.f);
        acc[2] += v * ((c8 + 2 < sz) ? e0.z : 0.f);
        acc[3] += v * ((c8 + 3 < sz) ? e0.w : 0.f);
        acc[4] += v * ((c8 + 4 < sz) ? e1.x : 0.f);
        acc[5] += v * ((c8 + 5 < sz) ? e1.y : 0.f);
        acc[6] += v * ((c8 + 6 < sz) ? e1.z : 0.f);
        acc[7] += v * ((c8 + 7 < sz) ? e1.w : 0.f);
    }
    uint4 o;
    o.x = f2bf(acc[0]) | (f2bf(acc[1]) << 16);
    o.y = f2bf(acc[2]) | (f2bf(acc[3]) << 16);
    o.z = f2bf(acc[4]) | (f2bf(acc[5]) << 16);
    o.w = f2bf(acc[6]) | (f2bf(acc[7]) << 16);
    *(uint4*)(y1 + (size_t)r * 32 + (tid & 7) * 4) = o;
}

// ---------------------------------------------------------------------------
// Layer-2 bf16 SPMM, flag2 rows only: x2[r] = sum val * y1[col].
// ---------------------------------------------------------------------------
__global__ void k_spmm2(const int* __restrict__ row_ptr, const int* __restrict__ pcol,
                        const float* __restrict__ dinv, const char* __restrict__ flag2,
                        const unsigned* __restrict__ y1, unsigned* __restrict__ x2) {
    int tid = blockIdx.x * blockDim.x + threadIdx.x;
    int r = tid >> 3;
    if (r >= NNODES) return;
    if (!flag2[r]) return;
    int cp = (tid & 7) << 2;
    int s = row_ptr[r];
    int e = row_ptr[r + 1];
    float dr = dinv[r];
    float acc[8] = {0.f, 0.f, 0.f, 0.f, 0.f, 0.f, 0.f, 0.f};
    int i = s;
    for (; i + 1 < e; i += 2) {
        int c0 = pcol[i], c1 = pcol[i + 1];
        float v0 = dr * dinv[c0], v1 = dr * dinv[c1];
        uint4 w0 = *(const uint4*)(y1 + (size_t)c0 * 32 + cp);
        uint4 w1 = *(const uint4*)(y1 + (size_t)c1 * 32 + cp);
        unpack_fma(acc, w0, v0);
        unpack_fma(acc, w1, v1);
    }
    if (i < e) {
        int c0 = pcol[i];
        float v0 = dr * dinv[c0];
        uint4 w0 = *(const uint4*)(y1 + (size_t)c0 * 32 + cp);
        unpack_fma(acc, w0, v0);
    }
    uint4 o;
    o.x = f2bf(acc[0]) | (f2bf(acc[1]) << 16);
    o.y = f2bf(acc[2]) | (f2bf(acc[3]) << 16);
    o.z = f2bf(acc[4]) | (f2bf(acc[5]) << 16);
    o.w = f2bf(acc[6]) | (f2bf(acc[7]) << 16);
    *(uint4*)(x2 + (size_t)r * 32 + cp) = o;
}

// ---------------------------------------------------------------------------
// Final sampled layer, everything fused:
//   x0r   = masked f32 emb row (exact)
//   out[slot]      = (x0r + y1[r] + x2[r] + sum val * x2[col]) * 0.25
//   out[3B + slot] = x0r                     (ego)
// ---------------------------------------------------------------------------
__global__ void k_spmm3(const int* __restrict__ row_ptr, const int* __restrict__ pcol,
                        const float* __restrict__ dinv, const int* __restrict__ sizes,
                        const float* __restrict__ ue, const float* __restrict__ ie,
                        const unsigned* __restrict__ y1, const unsigned* __restrict__ x2,
                        const int* __restrict__ users, const int* __restrict__ pos,
                        const int* __restrict__ neg, float* __restrict__ out) {
    int tid = blockIdx.x * blockDim.x + threadIdx.x;
    int slot = tid >> 3;
    if (slot >= 3 * B) return;
    int cp = (tid & 7) << 2;          // uint base
    int c8 = (tid & 7) << 3;          // f32 col base
    int set = slot / B;
    int b = slot - set * B;
    int r;
    if (set == 0)      r = users[b];
    else if (set == 1) r = N_USERS + pos[b];
    else               r = N_USERS + neg[b];
    int s = row_ptr[r];
    int e = row_ptr[r + 1];
    float dr = dinv[r];
    float acc[8] = {0.f, 0.f, 0.f, 0.f, 0.f, 0.f, 0.f, 0.f};
    uint4 g1 = *(const uint4*)(y1 + (size_t)r * 32 + cp);
    uint4 g2 = *(const uint4*)(x2 + (size_t)r * 32 + cp);
    unpack_fma(acc, g1, 1.0f);
    unpack_fma(acc, g2, 1.0f);
    int i = s;
    for (; i + 1 < e; i += 2) {
        int c0 = pcol[i], c1 = pcol[i + 1];
        float v0 = dr * dinv[c0], v1 = dr * dinv[c1];
        uint4 w0 = *(const uint4*)(x2 + (size_t)c0 * 32 + cp);
        uint4 w1 = *(const uint4*)(x2 + (size_t)c1 * 32 + cp);
        unpack_fma(acc, w0, v0);
        unpack_fma(acc, w1, v1);
    }
    if (i < e) {
        int c0 = pcol[i];
        float v0 = dr * dinv[c0];
        uint4 w0 = *(const uint4*)(x2 + (size_t)c0 * 32 + cp);
        unpack_fma(acc, w0, v0);
    }
    // exact masked f32 ego row
    const float* p = ((r < N_USERS) ? ue + (size_t)r * D
                                    : ie + (size_t)(r - N_USERS) * D) + c8;
    float4 e0 = *(const float4*)p;
    float4 e1 = *(const float4*)(p + 4);
    int sz = sizes[r];
    e0.x = (c8 + 0 < sz) ? e0.x : 0.f; e0.y = (c8 + 1 < sz) ? e0.y : 0.f;
    e0.z = (c8 + 2 < sz) ? e0.z : 0.f; e0.w = (c8 + 3 < sz) ? e0.w : 0.f;
    e1.x = (c8 + 4 < sz) ? e1.x : 0.f; e1.y = (c8 + 5 < sz) ? e1.y : 0.f;
    e1.z = (c8 + 6 < sz) ? e1.z : 0.f; e1.w = (c8 + 7 < sz) ? e1.w : 0.f;
    float4 oa, ob;
    oa.x = (e0.x + acc[0]) * 0.25f; oa.y = (e0.y + acc[1]) * 0.25f;
    oa.z = (e0.z + acc[2]) * 0.25f; oa.w = (e0.w + acc[3]) * 0.25f;
    ob.x = (e1.x + acc[4]) * 0.25f; ob.y = (e1.y + acc[5]) * 0.25f;
    ob.z = (e1.z + acc[6]) * 0.25f; ob.w = (e1.w + acc[7]) * 0.25f;
    float* o0 = out + (size_t)slot * D + c8;
    float* o1 = out + (size_t)(3 * B + slot) * D + c8;
    *(float4*)o0 = oa; *(float4*)(o0 + 4) = ob;
    *(float4*)o1 = e0; *(float4*)(o1 + 4) = e1;
}

extern "C" void kernel_launch(void* const* d_in, const int* in_sizes, int n_in,
                              void* d_out, int out_size, void* d_ws, size_t ws_size,
                              hipStream_t stream) {
    const float* ue   = (const float*)d_in[0];
    const float* ie   = (const float*)d_in[1];
    const int*   um   = (const int*)d_in[2];
    const int*   im   = (const int*)d_in[3];
    const int*   rows = (const int*)d_in[4];
    const int*   cols = (const int*)d_in[5];
    const int*   users = (const int*)d_in[7];
    const int*   pos   = (const int*)d_in[8];
    const int*   neg   = (const int*)d_in[9];
    int nnz = in_sizes[4];

    float* out = (float*)d_out;

    // workspace layout (16B-aligned bf16 node buffers first)
    unsigned short* Y1 = (unsigned short*)d_ws;         // NNODES*D bf16
    unsigned short* X2 = Y1 + (size_t)NNODES * D;       // NNODES*D bf16
    int*   deg     = (int*)(X2 + (size_t)NNODES * D);   // NNODES
    int*   row_ptr = deg + NNODES;                      // NNODES+1
    int*   nextp   = row_ptr + NNODES + 1;              // NNODES
    int*   sizes   = nextp + NNODES;                    // NNODES
    int*   sums    = sizes + NNODES;                    // up to 4096
    float* dinv    = (float*)(sums + 4096);             // NNODES
    int*   pcol    = (int*)(dinv + NNODES);             // nnz
    char*  flag1   = (char*)(pcol + nnz);               // NNODES
    char*  flag2   = flag1 + NNODES;                    // NNODES

    const int blk = 256;
    const int scan_blocks = (NNODES + 255) / 256;       // 2344

    // --- CSR build + flag clear ---
    hipMemsetAsync(deg, 0, (size_t)NNODES * sizeof(int), stream);
    hipMemsetAsync(flag1, 0, (size_t)2 * NNODES, stream);
    k_hist<<<(nnz + blk - 1) / blk, blk, 0, stream>>>(rows, deg, nnz);
    k_scan1<<<scan_blocks, 256, 0, stream>>>(deg, sums, dinv, NNODES);
    k_scan2<<<1, 1024, 0, stream>>>(sums, scan_blocks);
    k_scan3<<<(NNODES + blk - 1) / blk, blk, 0, stream>>>(deg, sums, row_ptr, nextp, nnz);
    k_scatter<<<(nnz + blk - 1) / blk, blk, 0, stream>>>(rows, cols, nextp, pcol, nnz);

    // --- prefix-mask sizes (only pass over the masks) ---
    k_sizes<<<(NNODES * 64 + blk - 1) / blk, blk, 0, stream>>>(um, im, sizes);

    // --- frontier marking ---
    k_mark_s<<<(3 * B + blk - 1) / blk, blk, 0, stream>>>(row_ptr, pcol, users, pos, neg,
                                                          flag1, flag2);
    k_mark_1<<<(NNODES + blk - 1) / blk, blk, 0, stream>>>(row_ptr, pcol, flag2, flag1);

    int n_full = NNODES * 8;
    int n_samp = 3 * B * 8;

    // layer 1 (flag1 rows): Y1 = A * masked_emb
    k_spmm1<<<(n_full + blk - 1) / blk, blk, 0, stream>>>(row_ptr, pcol, dinv, sizes, flag1,
                                                          ue, ie, (unsigned*)Y1);

    // layer 2 (flag2 rows): X2 = A * Y1
    k_spmm2<<<(n_full + blk - 1) / blk, blk, 0, stream>>>(row_ptr, pcol, dinv, flag2,
                                                          (const unsigned*)Y1, (unsigned*)X2);

    // layer 3: sampled rows, fully fused epilogue + ego
    k_spmm3<<<(n_samp + blk - 1) / blk, blk, 0, stream>>>(row_ptr, pcol, dinv, sizes,
                                                          ue, ie,
                                                          (const unsigned*)Y1,
                                                          (const unsigned*)X2,
                                                          users, pos, neg, out);
}